// Round 4
// baseline (773.518 us; speedup 1.0000x reference)
//
#include <hip/hip_runtime.h>
#include <cmath>

#define S_TOTAL 32768   // BATCH*SEQ
#define LSEQ    2048
#define NBATCH  16
#define DM      256
#define DI      512
#define DSTATE  16
#define DTRANK  16
#define NCHUNK  16
#define CHUNK   128     // LSEQ / NCHUNK

typedef __attribute__((ext_vector_type(8))) short short8;
typedef __attribute__((ext_vector_type(4))) float f32x4;

__device__ __forceinline__ unsigned short f2bf(float f) {
    union { float f; unsigned int u; } v; v.f = f;
    const unsigned int r = v.u + 0x7fffu + ((v.u >> 16) & 1u);
    return (unsigned short)(r >> 16);
}
__device__ __forceinline__ float bf2f(unsigned short h) {
    union { unsigned int u; float f; } v; v.u = ((unsigned int)h) << 16;
    return v.f;
}
__device__ __forceinline__ float gelu_exact(float x) {
    return 0.5f * x * (1.0f + erff(x * 0.70710678118654752440f));
}
__device__ __forceinline__ float softplus_f(float x) {
    return x > 20.0f ? x : log1pf(expf(x));
}

enum { EPI_NONE = 0, EPI_GELU_BIAS = 1, EPI_RESID16 = 2, EPI_BIAS_RESID16 = 3 };

// ---------------------------------------------------------------------------
// bf16 MFMA GEMM: C[M,N] = epi(A[M,K](bf16) @ W[N,K](bf16)^T)
// 128x128 tile, BK=64, 4 waves, 16x16x32 MFMA, global_load_lds staging with
// pre-swizzled source + XOR'd ds_read (2-way banks). 2-phase pipeline.
// Residuals (when used) are bf16.
// ---------------------------------------------------------------------------
template <int EPI, bool OUTBF>
__global__ __launch_bounds__(256, 2) void gemm_bf16(
    const unsigned short* __restrict__ A, int lda,
    const unsigned short* __restrict__ W, int ldw,
    const float* __restrict__ bias,
    const unsigned short* __restrict__ resid, int ldr,
    void* __restrict__ Cout, int ldc, int nstore,
    int K, int nclampW)
{
    __shared__ unsigned short lds[2][2][8192];   // [buf][A/W][128*64] = 64 KB

    const int tid = threadIdx.x;
    const int w = tid >> 6, l = tid & 63;
    const int brow = blockIdx.y * 128, bcol = blockIdx.x * 128;
    const int wr = w >> 1, wc = w & 1;
    const int lr = l & 15, lh = l >> 4;

    f32x4 acc[4][4];
    #pragma unroll
    for (int m = 0; m < 4; ++m)
        #pragma unroll
        for (int n = 0; n < 4; ++n)
            acc[m][n] = f32x4{0.f, 0.f, 0.f, 0.f};

    auto stage = [&](int buf, int k0) {
        const int gslot = (l & 7) ^ (l >> 3);
        #pragma unroll
        for (int i = 0; i < 4; ++i) {
            const int row = i * 32 + w * 8 + (l >> 3);
            {
                const unsigned short* g =
                    A + (size_t)(brow + row) * lda + k0 + gslot * 8;
                const unsigned short* lp = &lds[buf][0][i * 2048 + w * 512];
                __builtin_amdgcn_global_load_lds(
                    (const __attribute__((address_space(1))) void*)g,
                    (__attribute__((address_space(3))) void*)lp, 16, 0, 0);
            }
            {
                int grow = bcol + row; if (grow > nclampW) grow = nclampW;
                const unsigned short* g =
                    W + (size_t)grow * ldw + k0 + gslot * 8;
                const unsigned short* lp = &lds[buf][1][i * 2048 + w * 512];
                __builtin_amdgcn_global_load_lds(
                    (const __attribute__((address_space(1))) void*)g,
                    (__attribute__((address_space(3))) void*)lp, 16, 0, 0);
            }
        }
    };

    stage(0, 0);
    __syncthreads();

    const int nkt = K >> 6;
    for (int t = 0; t < nkt; ++t) {
        if (t + 1 < nkt) stage((t + 1) & 1, (t + 1) << 6);
        const unsigned short* la = &lds[t & 1][0][0];
        const unsigned short* lb = &lds[t & 1][1][0];
        #pragma unroll
        for (int kk = 0; kk < 2; ++kk) {
            short8 af[4], bw[4];
            #pragma unroll
            for (int m = 0; m < 4; ++m) {
                const int row = wr * 64 + m * 16 + lr;
                const int slot = (kk * 4 + lh) ^ (row & 7);
                af[m] = *(const short8*)(la + row * 64 + slot * 8);
            }
            #pragma unroll
            for (int n = 0; n < 4; ++n) {
                const int row = wc * 64 + n * 16 + lr;
                const int slot = (kk * 4 + lh) ^ (row & 7);
                bw[n] = *(const short8*)(lb + row * 64 + slot * 8);
            }
            #pragma unroll
            for (int m = 0; m < 4; ++m)
                #pragma unroll
                for (int n = 0; n < 4; ++n)
                    acc[m][n] = __builtin_amdgcn_mfma_f32_16x16x32_bf16(
                        af[m], bw[n], acc[m][n], 0, 0, 0);
        }
        __syncthreads();
    }

    #pragma unroll
    for (int m = 0; m < 4; ++m) {
        #pragma unroll
        for (int j = 0; j < 4; ++j) {
            const int rg = brow + wr * 64 + m * 16 + lh * 4 + j;
            #pragma unroll
            for (int n = 0; n < 4; ++n) {
                const int cg = bcol + wc * 64 + n * 16 + lr;
                if (cg < nstore) {
                    float v = acc[m][n][j];
                    if (EPI == EPI_GELU_BIAS) {
                        v = gelu_exact(v + bias[cg]);
                    } else if (EPI == EPI_RESID16) {
                        v += bf2f(resid[(size_t)rg * ldr + cg]);
                    } else if (EPI == EPI_BIAS_RESID16) {
                        v += bias[cg] + bf2f(resid[(size_t)rg * ldr + cg]);
                    }
                    if (OUTBF)
                        ((unsigned short*)Cout)[(size_t)rg * ldc + cg] = f2bf(v);
                    else
                        ((float*)Cout)[(size_t)rg * ldc + cg] = v;
                }
            }
        }
    }
}

// ---------------------------------------------------------------------------
// Convert x (f32 -> bf16) and the 5 GEMM weight matrices.
// ---------------------------------------------------------------------------
__global__ __launch_bounds__(256) void convert_kernel(
    const float* __restrict__ x,   const float* __restrict__ win,
    const float* __restrict__ wxp, const float* __restrict__ wop,
    const float* __restrict__ w1,  const float* __restrict__ w2,
    unsigned short* __restrict__ x16, unsigned short* __restrict__ wb)
{
    int idx = blockIdx.x * 256 + threadIdx.x;
    const int NX = S_TOTAL * DM;                         // 8388608
    if (idx < NX) { x16[idx] = f2bf(x[idx]); return; }
    idx -= NX;
    if (idx < 262144) { wb[idx] = f2bf(win[idx]); return; }
    idx -= 262144;
    if (idx < 24576)  { wb[262144 + idx] = f2bf(wxp[idx]); return; }
    idx -= 24576;
    if (idx < 131072) { wb[286720 + idx] = f2bf(wop[idx]); return; }
    idx -= 131072;
    if (idx < 262144) { wb[417792 + idx] = f2bf(w1[idx]); return; }
    idx -= 262144;
    if (idx < 262144) { wb[679936 + idx] = f2bf(w2[idx]); return; }
}

// ---------------------------------------------------------------------------
// Depthwise causal conv1d (width 4, bf16 in from uz[:, 0:512]) + bias + SiLU.
// Thread = 8 channels. Output bf16 only.
// ---------------------------------------------------------------------------
__global__ __launch_bounds__(256) void conv_silu_kernel(
    const unsigned short* __restrict__ uz, const float* __restrict__ cw,
    const float* __restrict__ cb, unsigned short* __restrict__ uch)
{
    const int idx = blockIdx.x * 256 + threadIdx.x;   // < S_TOTAL*64
    const int g = idx & 63;
    const int s = idx >> 6;
    const int l = s & (LSEQ - 1);
    const int c0 = g * 8;

    float acc[8];
    float4 cwv[8];
    #pragma unroll
    for (int j = 0; j < 8; ++j) {
        acc[j] = cb[c0 + j];
        cwv[j] = *(const float4*)(cw + (c0 + j) * 4);
    }
    #pragma unroll
    for (int t = 0; t < 4; ++t) {
        const int lt = l - 3 + t;
        if (lt >= 0) {
            const short8 uv = *(const short8*)(uz + (s - 3 + t) * 1024 + c0);
            #pragma unroll
            for (int j = 0; j < 8; ++j) {
                const float wt = (t == 0) ? cwv[j].x : (t == 1) ? cwv[j].y
                               : (t == 2) ? cwv[j].z : cwv[j].w;
                acc[j] += bf2f((unsigned short)uv[j]) * wt;
            }
        }
    }
    short8 ob;
    #pragma unroll
    for (int j = 0; j < 8; ++j) {
        const float sig = 1.0f / (1.0f + __expf(-acc[j]));
        ob[j] = (short)f2bf(acc[j] * sig);
    }
    *(short8*)(uch + s * DI + c0) = ob;
}

// ---------------------------------------------------------------------------
// dt_proj + softplus: delta[s,c] = softplus(sum_r xdbl[s,r]*dtw[c,r] + dtb[c])
// Thread computes 4 consecutive channels of one row.
// ---------------------------------------------------------------------------
__global__ __launch_bounds__(256) void dt_kernel(
    const float* __restrict__ xdbl, const float* __restrict__ dtw,
    const float* __restrict__ dtb, float* __restrict__ delta)
{
    const int idx = blockIdx.x * 256 + threadIdx.x;    // S_TOTAL*128
    const int s = idx >> 7, c0 = (idx & 127) << 2;

    float xr[16];
    *(float4*)&xr[0]  = *(const float4*)(xdbl + s * 64 + 0);
    *(float4*)&xr[4]  = *(const float4*)(xdbl + s * 64 + 4);
    *(float4*)&xr[8]  = *(const float4*)(xdbl + s * 64 + 8);
    *(float4*)&xr[12] = *(const float4*)(xdbl + s * 64 + 12);

    const float4 bb = *(const float4*)(dtb + c0);
    float accd[4] = {bb.x, bb.y, bb.z, bb.w};
    #pragma unroll
    for (int j = 0; j < 4; ++j) {
        const float* wr = dtw + (c0 + j) * 16;
        float a = accd[j];
        #pragma unroll
        for (int rq = 0; rq < 4; ++rq) {
            const float4 wv = *(const float4*)(wr + rq * 4);
            a += xr[rq*4+0] * wv.x + xr[rq*4+1] * wv.y
               + xr[rq*4+2] * wv.z + xr[rq*4+3] * wv.w;
        }
        accd[j] = softplus_f(a);
    }
    *(float4*)(delta + s * DI + c0) =
        make_float4(accd[0], accd[1], accd[2], accd[3]);
}

// ---------------------------------------------------------------------------
// Chunked selective scan, v2: int32 offsets, clamped branch-free prefetch,
// bf16 u/z, P = exp(a * sum(d)) algebraic shortcut.
// Layout: 4 lanes per channel (one per 4-state quad), 64 channels per block.
// ---------------------------------------------------------------------------
__global__ __launch_bounds__(256) void scan_p1(
    const float* __restrict__ delta, const unsigned short* __restrict__ uch,
    const float* __restrict__ xdbl, const float* __restrict__ A_log,
    float* __restrict__ P, float* __restrict__ Q)
{
    const int tid = threadIdx.x;
    const int cg = blockIdx.x & 7, k = (blockIdx.x >> 3) & 15, b = blockIdx.x >> 7;
    const int c = (cg << 6) + (tid >> 2), nq = (tid & 3) << 2;

    const float4 al = *(const float4*)(A_log + c * DSTATE + nq);
    const float4 a4 = {-__expf(al.x), -__expf(al.y), -__expf(al.z), -__expf(al.w)};

    float4 h4 = {0, 0, 0, 0};
    float sumd = 0.f;

    const int base = (b * LSEQ + k * CHUNK) * DI + c;
    const int xb   = (b * LSEQ + k * CHUNK) * 64 + DTRANK + nq;

    float  dA_ = delta[base];
    float  uA_ = bf2f(uch[base]);
    float4 BA_ = *(const float4*)(xdbl + xb);
    float  dB_ = delta[base + DI];
    float  uB_ = bf2f(uch[base + DI]);
    float4 BB_ = *(const float4*)(xdbl + xb + 64);

    for (int l = 0; l < CHUNK; l += 2) {
        const int lc = (l + 2 < CHUNK) ? (l + 2) : (CHUNK - 2);
        const int o2 = base + lc * DI;
        const int x2 = xb + lc * 64;
        const float  dC_ = delta[o2];
        const float  dD_ = delta[o2 + DI];
        const float  uC_ = bf2f(uch[o2]);
        const float  uD_ = bf2f(uch[o2 + DI]);
        const float4 BC_ = *(const float4*)(xdbl + x2);
        const float4 BD_ = *(const float4*)(xdbl + x2 + 64);

        {
            const float4 e = {__expf(dA_ * a4.x), __expf(dA_ * a4.y),
                              __expf(dA_ * a4.z), __expf(dA_ * a4.w)};
            const float du = dA_ * uA_;
            h4.x = h4.x * e.x + du * BA_.x;
            h4.y = h4.y * e.y + du * BA_.y;
            h4.z = h4.z * e.z + du * BA_.z;
            h4.w = h4.w * e.w + du * BA_.w;
            sumd += dA_;
        }
        {
            const float4 e = {__expf(dB_ * a4.x), __expf(dB_ * a4.y),
                              __expf(dB_ * a4.z), __expf(dB_ * a4.w)};
            const float du = dB_ * uB_;
            h4.x = h4.x * e.x + du * BB_.x;
            h4.y = h4.y * e.y + du * BB_.y;
            h4.z = h4.z * e.z + du * BB_.z;
            h4.w = h4.w * e.w + du * BB_.w;
            sumd += dB_;
        }
        dA_ = dC_; uA_ = uC_; BA_ = BC_;
        dB_ = dD_; uB_ = uD_; BB_ = BD_;
    }

    const int pi = ((b * NCHUNK + k) * DI + c) * 16 + nq;
    const float4 P4 = {__expf(a4.x * sumd), __expf(a4.y * sumd),
                       __expf(a4.z * sumd), __expf(a4.w * sumd)};
    *(float4*)(P + pi) = P4;
    *(float4*)(Q + pi) = h4;
}

__global__ __launch_bounds__(256) void scan_p2(
    const float* __restrict__ P, const float* __restrict__ Q,
    float* __restrict__ HS)
{
    const int t  = blockIdx.x * 256 + threadIdx.x;   // 32768
    const int nq = (t & 3) << 2;
    const int c  = (t >> 2) & (DI - 1);
    const int b  = t >> 11;
    float4 hs = {0, 0, 0, 0};
    for (int k = 0; k < NCHUNK; ++k) {
        const int idx = ((b * NCHUNK + k) * DI + c) * 16 + nq;
        if (k > 0) {
            const int ip = idx - DI * 16;
            const float4 p4 = *(const float4*)(P + ip);
            const float4 q4 = *(const float4*)(Q + ip);
            hs.x = hs.x * p4.x + q4.x;
            hs.y = hs.y * p4.y + q4.y;
            hs.z = hs.z * p4.z + q4.z;
            hs.w = hs.w * p4.w + q4.w;
        }
        *(float4*)(HS + idx) = hs;
    }
}

__global__ __launch_bounds__(256) void scan_p3(
    const float* __restrict__ delta, const unsigned short* __restrict__ uch,
    const float* __restrict__ xdbl, const unsigned short* __restrict__ zuz,
    const float* __restrict__ A_log, const float* __restrict__ Dskip,
    const float* __restrict__ HS, unsigned short* __restrict__ y)
{
    const int tid = threadIdx.x;
    const int cg = blockIdx.x & 7, k = (blockIdx.x >> 3) & 15, b = blockIdx.x >> 7;
    const int c = (cg << 6) + (tid >> 2), nq = (tid & 3) << 2;

    const float4 al = *(const float4*)(A_log + c * DSTATE + nq);
    const float4 a4 = {-__expf(al.x), -__expf(al.y), -__expf(al.z), -__expf(al.w)};
    const float dsk = Dskip[c];

    const int pi = ((b * NCHUNK + k) * DI + c) * 16 + nq;
    float4 h4 = *(const float4*)(HS + pi);

    const int base = (b * LSEQ + k * CHUNK) * DI + c;
    const int xb   = (b * LSEQ + k * CHUNK) * 64 + DTRANK + nq;
    const int zb   = (b * LSEQ + k * CHUNK) * 1024 + c;

    float  dA_ = delta[base];
    float  uA_ = bf2f(uch[base]);
    float  zA_ = bf2f(zuz[zb]);
    float4 BA_ = *(const float4*)(xdbl + xb);
    float4 CA_ = *(const float4*)(xdbl + xb + DSTATE);
    float  dB_ = delta[base + DI];
    float  uB_ = bf2f(uch[base + DI]);
    float  zB_ = bf2f(zuz[zb + 1024]);
    float4 BB_ = *(const float4*)(xdbl + xb + 64);
    float4 CB_ = *(const float4*)(xdbl + xb + 64 + DSTATE);

    for (int l = 0; l < CHUNK; l += 2) {
        const int lc = (l + 2 < CHUNK) ? (l + 2) : (CHUNK - 2);
        const int o2 = base + lc * DI;
        const int x2 = xb + lc * 64;
        const int z2 = zb + lc * 1024;
        const float  dC_ = delta[o2];
        const float  dD_ = delta[o2 + DI];
        const float  uC_ = bf2f(uch[o2]);
        const float  uD_ = bf2f(uch[o2 + DI]);
        const float  zC_ = bf2f(zuz[z2]);
        const float  zD_ = bf2f(zuz[z2 + 1024]);
        const float4 BC_ = *(const float4*)(xdbl + x2);
        const float4 CC_ = *(const float4*)(xdbl + x2 + DSTATE);
        const float4 BD_ = *(const float4*)(xdbl + x2 + 64);
        const float4 CD_ = *(const float4*)(xdbl + x2 + 64 + DSTATE);

        {
            const float4 e = {__expf(dA_ * a4.x), __expf(dA_ * a4.y),
                              __expf(dA_ * a4.z), __expf(dA_ * a4.w)};
            const float du = dA_ * uA_;
            h4.x = h4.x * e.x + du * BA_.x;
            h4.y = h4.y * e.y + du * BA_.y;
            h4.z = h4.z * e.z + du * BA_.z;
            h4.w = h4.w * e.w + du * BA_.w;
            float yp = h4.x * CA_.x + h4.y * CA_.y + h4.z * CA_.z + h4.w * CA_.w;
            yp += __shfl_xor(yp, 1);
            yp += __shfl_xor(yp, 2);
            if ((tid & 3) == 0) {
                const float sg = 1.0f / (1.0f + __expf(-zA_));
                y[base + l * DI] = f2bf((yp + uA_ * dsk) * (zA_ * sg));
            }
        }
        {
            const float4 e = {__expf(dB_ * a4.x), __expf(dB_ * a4.y),
                              __expf(dB_ * a4.z), __expf(dB_ * a4.w)};
            const float du = dB_ * uB_;
            h4.x = h4.x * e.x + du * BB_.x;
            h4.y = h4.y * e.y + du * BB_.y;
            h4.z = h4.z * e.z + du * BB_.z;
            h4.w = h4.w * e.w + du * BB_.w;
            float yp = h4.x * CB_.x + h4.y * CB_.y + h4.z * CB_.z + h4.w * CB_.w;
            yp += __shfl_xor(yp, 1);
            yp += __shfl_xor(yp, 2);
            if ((tid & 3) == 0) {
                const float sg = 1.0f / (1.0f + __expf(-zB_));
                y[base + (l + 1) * DI] = f2bf((yp + uB_ * dsk) * (zB_ * sg));
            }
        }
        dA_ = dC_; uA_ = uC_; zA_ = zC_; BA_ = BC_; CA_ = CC_;
        dB_ = dD_; uB_ = uD_; zB_ = zD_; BB_ = BD_; CB_ = CD_;
    }
}

// ---------------------------------------------------------------------------
// LayerNorm over rows of 256; optional f32 and/or bf16 outputs.
// ---------------------------------------------------------------------------
__global__ __launch_bounds__(256) void layernorm256_kernel(
    const float* __restrict__ in, const float* __restrict__ g,
    const float* __restrict__ b, float* __restrict__ out,
    unsigned short* __restrict__ out16)
{
    const int wave = threadIdx.x >> 6;
    const int lane = threadIdx.x & 63;
    const int row  = blockIdx.x * 4 + wave;

    const float4 v = ((const float4*)(in + (size_t)row * DM))[lane];
    float s  = v.x + v.y + v.z + v.w;
    float sq = v.x * v.x + v.y * v.y + v.z * v.z + v.w * v.w;
    #pragma unroll
    for (int o = 1; o < 64; o <<= 1) {
        s  += __shfl_xor(s, o);
        sq += __shfl_xor(sq, o);
    }
    const float mu  = s * (1.0f / 256.0f);
    const float var = sq * (1.0f / 256.0f) - mu * mu;
    const float rs  = rsqrtf(var + 1e-12f);

    const float4 gg = ((const float4*)g)[lane];
    const float4 bb = ((const float4*)b)[lane];
    float4 o4;
    o4.x = (v.x - mu) * rs * gg.x + bb.x;
    o4.y = (v.y - mu) * rs * gg.y + bb.y;
    o4.z = (v.z - mu) * rs * gg.z + bb.z;
    o4.w = (v.w - mu) * rs * gg.w + bb.w;
    if (out)
        ((float4*)(out + (size_t)row * DM))[lane] = o4;
    if (out16) {
        uint2 p;
        p.x = (unsigned int)f2bf(o4.x) | ((unsigned int)f2bf(o4.y) << 16);
        p.y = (unsigned int)f2bf(o4.z) | ((unsigned int)f2bf(o4.w) << 16);
        *(uint2*)(out16 + (size_t)row * DM + lane * 4) = p;
    }
}

// ---------------------------------------------------------------------------
extern "C" void kernel_launch(void* const* d_in, const int* in_sizes, int n_in,
                              void* d_out, int out_size, void* d_ws, size_t ws_size,
                              hipStream_t stream)
{
    const float* x          = (const float*)d_in[0];
    const float* in_proj_w  = (const float*)d_in[1];
    const float* conv_w     = (const float*)d_in[2];
    const float* conv_b     = (const float*)d_in[3];
    const float* x_proj_w   = (const float*)d_in[4];
    const float* dt_proj_w  = (const float*)d_in[5];
    const float* dt_proj_b  = (const float*)d_in[6];
    const float* A_log      = (const float*)d_in[7];
    const float* Dskip      = (const float*)d_in[8];
    const float* out_proj_w = (const float*)d_in[9];
    const float* ln1_g      = (const float*)d_in[10];
    const float* ln1_b      = (const float*)d_in[11];
    const float* w1         = (const float*)d_in[12];
    const float* b1         = (const float*)d_in[13];
    const float* w2         = (const float*)d_in[14];
    const float* b2         = (const float*)d_in[15];
    const float* ln2_g      = (const float*)d_in[16];
    const float* ln2_b      = (const float*)d_in[17];
    float* out = (float*)d_out;
    char*  ws8 = (char*)d_ws;

    const size_t Mi = 1048576;
    // Workspace map (byte offsets, ~194 MiB used):
    //  [  0, 64Mi): uz bf16 [S,1024]    -> after p3: M f32 [0,32Mi), F2 f32 [32,64Mi)
    //  [ 64, 96Mi): uch bf16 [S,512]    -> y bf16 in-place
    //  [ 96,104Mi): x_dbl f32 [S,64]
    //  [104,168Mi): delta f32 [S,512]   -> after p3: FF bf16 [S,1024]
    //  [168,176Mi): P f32; [176,184Mi): Q f32   -> after p2: H1h bf16 [168,184Mi)
    //  [184,192Mi): HS f32
    //  [192,194Mi): bf16 weights
    unsigned short* bufUZ  = (unsigned short*)(ws8);
    unsigned short* bufUCh = (unsigned short*)(ws8 + 64 * Mi);
    float*          bufXD  = (float*)(ws8 + 96 * Mi);
    float*          bufDel = (float*)(ws8 + 104 * Mi);
    float*          bufP   = (float*)(ws8 + 168 * Mi);
    float*          bufQ   = (float*)(ws8 + 176 * Mi);
    float*          bufHS  = (float*)(ws8 + 184 * Mi);
    unsigned short* wb     = (unsigned short*)(ws8 + 192 * Mi);

    float*          bufM   = (float*)(ws8);                      // over uz lo
    float*          bufF2  = (float*)(ws8 + 32 * Mi);            // over uz hi
    unsigned short* bufFF  = (unsigned short*)(ws8 + 104 * Mi);  // over delta
    unsigned short* bufH1h = (unsigned short*)(ws8 + 168 * Mi);  // over P,Q
    unsigned short* bufY   = bufUCh;

    unsigned short* wInP16 = wb;
    unsigned short* wXP16  = wb + 262144;
    unsigned short* wOP16  = wb + 286720;
    unsigned short* wW116  = wb + 417792;
    unsigned short* wW216  = wb + 679936;

    // x bf16 lives in d_out (dead after out_proj reads it as residual).
    unsigned short* x16 = (unsigned short*)d_out;

    const dim3 blk(256);
    const int MT = S_TOTAL / 128;   // 256 row tiles

    // 0) cast x + weights to bf16
    convert_kernel<<<dim3(36448), blk, 0, stream>>>(
        x, in_proj_w, x_proj_w, out_proj_w, w1, w2, x16, wb);

    // 1) in_proj (merged u|z) -> uz bf16 [S,1024]
    gemm_bf16<EPI_NONE, true><<<dim3(8, MT), blk, 0, stream>>>(
        x16, DM, wInP16, DM, nullptr, nullptr, 0, bufUZ, 1024, 1024, DM, 1023);

    // 2) depthwise causal conv + SiLU -> uch bf16
    conv_silu_kernel<<<dim3(S_TOTAL * 64 / 256), blk, 0, stream>>>(
        bufUZ, conv_w, conv_b, bufUCh);

    // 3) x_proj -> x_dbl f32 [S,64] (48 valid cols)
    gemm_bf16<EPI_NONE, false><<<dim3(1, MT), blk, 0, stream>>>(
        bufUCh, DI, wXP16, DI, nullptr, nullptr, 0, bufXD, 64, 64, DI, 47);

    // 4) dt_proj + softplus -> delta f32
    dt_kernel<<<dim3(S_TOTAL * 128 / 256), blk, 0, stream>>>(
        bufXD, dt_proj_w, dt_proj_b, bufDel);

    // 5) chunked selective scan -> y bf16 (in place over uch)
    scan_p1<<<dim3(NBATCH * NCHUNK * 8), blk, 0, stream>>>(
        bufDel, bufUCh, bufXD, A_log, bufP, bufQ);
    scan_p2<<<dim3(NBATCH * DI * 4 / 256), blk, 0, stream>>>(
        bufP, bufQ, bufHS);
    scan_p3<<<dim3(NBATCH * NCHUNK * 8), blk, 0, stream>>>(
        bufDel, bufUCh, bufXD, bufUZ + 512, A_log, Dskip, bufHS, bufY);

    // 6) out_proj + residual x (bf16) -> M f32 (pre-LN1)
    gemm_bf16<EPI_RESID16, false><<<dim3(2, MT), blk, 0, stream>>>(
        bufY, DI, wOP16, DI, nullptr, x16, DM, bufM, DM, 256, DI, 255);

    // 7) LN1 -> h1 bf16 only
    layernorm256_kernel<<<dim3(S_TOTAL / 4), blk, 0, stream>>>(
        bufM, ln1_g, ln1_b, nullptr, bufH1h);

    // 8) ff1: gelu(h1 @ w1^T + b1) -> FF bf16
    gemm_bf16<EPI_GELU_BIAS, true><<<dim3(8, MT), blk, 0, stream>>>(
        bufH1h, DM, wW116, DM, b1, nullptr, 0, bufFF, 1024, 1024, DM, 1023);

    // 9) ff2 + b2 + h1 (bf16 resid) -> F2 f32 (pre-LN2)
    gemm_bf16<EPI_BIAS_RESID16, false><<<dim3(2, MT), blk, 0, stream>>>(
        bufFF, 1024, wW216, 1024, b2, bufH1h, DM, bufF2, DM, 256, 1024, 255);

    // 10) LN2 -> out
    layernorm256_kernel<<<dim3(S_TOTAL / 4), blk, 0, stream>>>(
        bufF2, ln2_g, ln2_b, out, nullptr);
}

// Round 5
// 720.662 us; speedup vs baseline: 1.0733x; 1.0733x over previous
//
#include <hip/hip_runtime.h>
#include <cmath>

#define S_TOTAL 32768   // BATCH*SEQ
#define LSEQ    2048
#define NBATCH  16
#define DM      256
#define DI      512
#define DSTATE  16
#define DTRANK  16
#define NCHUNK  16
#define CHUNK   128     // LSEQ / NCHUNK

typedef __attribute__((ext_vector_type(8))) short short8;
typedef __attribute__((ext_vector_type(4))) float f32x4;

__device__ __forceinline__ unsigned short f2bf(float f) {
    union { float f; unsigned int u; } v; v.f = f;
    const unsigned int r = v.u + 0x7fffu + ((v.u >> 16) & 1u);
    return (unsigned short)(r >> 16);
}
__device__ __forceinline__ float bf2f(unsigned short h) {
    union { unsigned int u; float f; } v; v.u = ((unsigned int)h) << 16;
    return v.f;
}
__device__ __forceinline__ float gelu_exact(float x) {
    return 0.5f * x * (1.0f + erff(x * 0.70710678118654752440f));
}
__device__ __forceinline__ float softplus_f(float x) {
    return x > 20.0f ? x : log1pf(expf(x));
}

enum { EPI_NONE = 0, EPI_GELU_BIAS = 1, EPI_RESID16 = 2, EPI_BIAS_RESID16 = 3 };

// ---------------------------------------------------------------------------
// bf16 MFMA GEMM: C[M,N] = epi(A[M,K](bf16) @ W[N,K](bf16)^T)
// 128x128 tile, BK=64, 4 waves, 16x16x32 MFMA.
// T4 schedule: counted vmcnt(8) + raw s_barrier; prefetch loads stay in
// flight across barriers (never drain to 0 in the main loop).
// ---------------------------------------------------------------------------
template <int EPI, bool OUTBF>
__global__ __launch_bounds__(256, 2) void gemm_bf16(
    const unsigned short* __restrict__ A, int lda,
    const unsigned short* __restrict__ W, int ldw,
    const float* __restrict__ bias,
    const unsigned short* __restrict__ resid, int ldr,
    void* __restrict__ Cout, int ldc, int nstore,
    int K, int nclampW)
{
    __shared__ unsigned short lds[2][2][8192];   // [buf][A/W][128*64] = 64 KB

    const int tid = threadIdx.x;
    const int w = tid >> 6, l = tid & 63;
    const int brow = blockIdx.y * 128, bcol = blockIdx.x * 128;
    const int wr = w >> 1, wc = w & 1;
    const int lr = l & 15, lh = l >> 4;

    f32x4 acc[4][4];
    #pragma unroll
    for (int m = 0; m < 4; ++m)
        #pragma unroll
        for (int n = 0; n < 4; ++n)
            acc[m][n] = f32x4{0.f, 0.f, 0.f, 0.f};

    auto stage = [&](int buf, int k0) {
        const int gslot = (l & 7) ^ (l >> 3);
        #pragma unroll
        for (int i = 0; i < 4; ++i) {
            const int row = i * 32 + w * 8 + (l >> 3);
            {
                const unsigned short* g =
                    A + (size_t)(brow + row) * lda + k0 + gslot * 8;
                const unsigned short* lp = &lds[buf][0][i * 2048 + w * 512];
                __builtin_amdgcn_global_load_lds(
                    (const __attribute__((address_space(1))) void*)g,
                    (__attribute__((address_space(3))) void*)lp, 16, 0, 0);
            }
            {
                int grow = bcol + row; if (grow > nclampW) grow = nclampW;
                const unsigned short* g =
                    W + (size_t)grow * ldw + k0 + gslot * 8;
                const unsigned short* lp = &lds[buf][1][i * 2048 + w * 512];
                __builtin_amdgcn_global_load_lds(
                    (const __attribute__((address_space(1))) void*)g,
                    (__attribute__((address_space(3))) void*)lp, 16, 0, 0);
            }
        }
    };

    stage(0, 0);                 // 8 VMEM ops per wave in flight

    const int nkt = K >> 6;
    for (int t = 0; t < nkt; ++t) {
        if (t + 1 < nkt) {
            stage((t + 1) & 1, (t + 1) << 6);   // +8 in flight
            __builtin_amdgcn_sched_barrier(0);
            // wait until only the 8 prefetch loads remain -> buf[t] landed
            asm volatile("s_waitcnt vmcnt(8)" ::: "memory");
        } else {
            __builtin_amdgcn_sched_barrier(0);
            asm volatile("s_waitcnt vmcnt(0)" ::: "memory");
        }
        __builtin_amdgcn_s_barrier();          // all waves: buf[t] ready
        __builtin_amdgcn_sched_barrier(0);

        const unsigned short* la = &lds[t & 1][0][0];
        const unsigned short* lb = &lds[t & 1][1][0];
        #pragma unroll
        for (int kk = 0; kk < 2; ++kk) {
            short8 af[4], bw[4];
            #pragma unroll
            for (int m = 0; m < 4; ++m) {
                const int row = wr * 64 + m * 16 + lr;
                const int slot = (kk * 4 + lh) ^ (row & 7);
                af[m] = *(const short8*)(la + row * 64 + slot * 8);
            }
            #pragma unroll
            for (int n = 0; n < 4; ++n) {
                const int row = wc * 64 + n * 16 + lr;
                const int slot = (kk * 4 + lh) ^ (row & 7);
                bw[n] = *(const short8*)(lb + row * 64 + slot * 8);
            }
            #pragma unroll
            for (int m = 0; m < 4; ++m)
                #pragma unroll
                for (int n = 0; n < 4; ++n)
                    acc[m][n] = __builtin_amdgcn_mfma_f32_16x16x32_bf16(
                        af[m], bw[n], acc[m][n], 0, 0, 0);
        }
        // all lds reads of buf[t] are consumed by MFMAs above (lgkm waited)
        __builtin_amdgcn_sched_barrier(0);
        asm volatile("s_waitcnt lgkmcnt(0)" ::: "memory");
        __builtin_amdgcn_s_barrier();          // safe to overwrite buf[t]
        __builtin_amdgcn_sched_barrier(0);
    }

    #pragma unroll
    for (int m = 0; m < 4; ++m) {
        #pragma unroll
        for (int j = 0; j < 4; ++j) {
            const int rg = brow + wr * 64 + m * 16 + lh * 4 + j;
            #pragma unroll
            for (int n = 0; n < 4; ++n) {
                const int cg = bcol + wc * 64 + n * 16 + lr;
                if (cg < nstore) {
                    float v = acc[m][n][j];
                    if (EPI == EPI_GELU_BIAS) {
                        v = gelu_exact(v + bias[cg]);
                    } else if (EPI == EPI_RESID16) {
                        v += bf2f(resid[(size_t)rg * ldr + cg]);
                    } else if (EPI == EPI_BIAS_RESID16) {
                        v += bias[cg] + bf2f(resid[(size_t)rg * ldr + cg]);
                    }
                    if (OUTBF)
                        ((unsigned short*)Cout)[(size_t)rg * ldc + cg] = f2bf(v);
                    else
                        ((float*)Cout)[(size_t)rg * ldc + cg] = v;
                }
            }
        }
    }
}

// ---------------------------------------------------------------------------
// Convert x (f32 -> bf16) and the 5 GEMM weight matrices.
// ---------------------------------------------------------------------------
__global__ __launch_bounds__(256) void convert_kernel(
    const float* __restrict__ x,   const float* __restrict__ win,
    const float* __restrict__ wxp, const float* __restrict__ wop,
    const float* __restrict__ w1,  const float* __restrict__ w2,
    unsigned short* __restrict__ x16, unsigned short* __restrict__ wb)
{
    int idx = blockIdx.x * 256 + threadIdx.x;
    const int NX = S_TOTAL * DM;                         // 8388608
    if (idx < NX) { x16[idx] = f2bf(x[idx]); return; }
    idx -= NX;
    if (idx < 262144) { wb[idx] = f2bf(win[idx]); return; }
    idx -= 262144;
    if (idx < 24576)  { wb[262144 + idx] = f2bf(wxp[idx]); return; }
    idx -= 24576;
    if (idx < 131072) { wb[286720 + idx] = f2bf(wop[idx]); return; }
    idx -= 131072;
    if (idx < 262144) { wb[417792 + idx] = f2bf(w1[idx]); return; }
    idx -= 262144;
    if (idx < 262144) { wb[679936 + idx] = f2bf(w2[idx]); return; }
}

// ---------------------------------------------------------------------------
// Depthwise causal conv1d (width 4, bf16 in from uz[:, 0:512]) + bias + SiLU.
// ---------------------------------------------------------------------------
__global__ __launch_bounds__(256) void conv_silu_kernel(
    const unsigned short* __restrict__ uz, const float* __restrict__ cw,
    const float* __restrict__ cb, unsigned short* __restrict__ uch)
{
    const int idx = blockIdx.x * 256 + threadIdx.x;   // < S_TOTAL*64
    const int g = idx & 63;
    const int s = idx >> 6;
    const int l = s & (LSEQ - 1);
    const int c0 = g * 8;

    float acc[8];
    float4 cwv[8];
    #pragma unroll
    for (int j = 0; j < 8; ++j) {
        acc[j] = cb[c0 + j];
        cwv[j] = *(const float4*)(cw + (c0 + j) * 4);
    }
    #pragma unroll
    for (int t = 0; t < 4; ++t) {
        const int lt = l - 3 + t;
        if (lt >= 0) {
            const short8 uv = *(const short8*)(uz + (s - 3 + t) * 1024 + c0);
            #pragma unroll
            for (int j = 0; j < 8; ++j) {
                const float wt = (t == 0) ? cwv[j].x : (t == 1) ? cwv[j].y
                               : (t == 2) ? cwv[j].z : cwv[j].w;
                acc[j] += bf2f((unsigned short)uv[j]) * wt;
            }
        }
    }
    short8 ob;
    #pragma unroll
    for (int j = 0; j < 8; ++j) {
        const float sig = 1.0f / (1.0f + __expf(-acc[j]));
        ob[j] = (short)f2bf(acc[j] * sig);
    }
    *(short8*)(uch + s * DI + c0) = ob;
}

// ---------------------------------------------------------------------------
// dt_proj + softplus.
// ---------------------------------------------------------------------------
__global__ __launch_bounds__(256) void dt_kernel(
    const float* __restrict__ xdbl, const float* __restrict__ dtw,
    const float* __restrict__ dtb, float* __restrict__ delta)
{
    const int idx = blockIdx.x * 256 + threadIdx.x;    // S_TOTAL*128
    const int s = idx >> 7, c0 = (idx & 127) << 2;

    float xr[16];
    *(float4*)&xr[0]  = *(const float4*)(xdbl + s * 64 + 0);
    *(float4*)&xr[4]  = *(const float4*)(xdbl + s * 64 + 4);
    *(float4*)&xr[8]  = *(const float4*)(xdbl + s * 64 + 8);
    *(float4*)&xr[12] = *(const float4*)(xdbl + s * 64 + 12);

    const float4 bb = *(const float4*)(dtb + c0);
    float accd[4] = {bb.x, bb.y, bb.z, bb.w};
    #pragma unroll
    for (int j = 0; j < 4; ++j) {
        const float* wr = dtw + (c0 + j) * 16;
        float a = accd[j];
        #pragma unroll
        for (int rq = 0; rq < 4; ++rq) {
            const float4 wv = *(const float4*)(wr + rq * 4);
            a += xr[rq*4+0] * wv.x + xr[rq*4+1] * wv.y
               + xr[rq*4+2] * wv.z + xr[rq*4+3] * wv.w;
        }
        accd[j] = softplus_f(a);
    }
    *(float4*)(delta + s * DI + c0) =
        make_float4(accd[0], accd[1], accd[2], accd[3]);
}

// ---------------------------------------------------------------------------
// Chunked selective scan (3 passes), v2.
// ---------------------------------------------------------------------------
__global__ __launch_bounds__(256) void scan_p1(
    const float* __restrict__ delta, const unsigned short* __restrict__ uch,
    const float* __restrict__ xdbl, const float* __restrict__ A_log,
    float* __restrict__ P, float* __restrict__ Q)
{
    const int tid = threadIdx.x;
    const int cg = blockIdx.x & 7, k = (blockIdx.x >> 3) & 15, b = blockIdx.x >> 7;
    const int c = (cg << 6) + (tid >> 2), nq = (tid & 3) << 2;

    const float4 al = *(const float4*)(A_log + c * DSTATE + nq);
    const float4 a4 = {-__expf(al.x), -__expf(al.y), -__expf(al.z), -__expf(al.w)};

    float4 h4 = {0, 0, 0, 0};
    float sumd = 0.f;

    const int base = (b * LSEQ + k * CHUNK) * DI + c;
    const int xb   = (b * LSEQ + k * CHUNK) * 64 + DTRANK + nq;

    float  dA_ = delta[base];
    float  uA_ = bf2f(uch[base]);
    float4 BA_ = *(const float4*)(xdbl + xb);
    float  dB_ = delta[base + DI];
    float  uB_ = bf2f(uch[base + DI]);
    float4 BB_ = *(const float4*)(xdbl + xb + 64);

    for (int l = 0; l < CHUNK; l += 2) {
        const int lc = (l + 2 < CHUNK) ? (l + 2) : (CHUNK - 2);
        const int o2 = base + lc * DI;
        const int x2 = xb + lc * 64;
        const float  dC_ = delta[o2];
        const float  dD_ = delta[o2 + DI];
        const float  uC_ = bf2f(uch[o2]);
        const float  uD_ = bf2f(uch[o2 + DI]);
        const float4 BC_ = *(const float4*)(xdbl + x2);
        const float4 BD_ = *(const float4*)(xdbl + x2 + 64);

        {
            const float4 e = {__expf(dA_ * a4.x), __expf(dA_ * a4.y),
                              __expf(dA_ * a4.z), __expf(dA_ * a4.w)};
            const float du = dA_ * uA_;
            h4.x = h4.x * e.x + du * BA_.x;
            h4.y = h4.y * e.y + du * BA_.y;
            h4.z = h4.z * e.z + du * BA_.z;
            h4.w = h4.w * e.w + du * BA_.w;
            sumd += dA_;
        }
        {
            const float4 e = {__expf(dB_ * a4.x), __expf(dB_ * a4.y),
                              __expf(dB_ * a4.z), __expf(dB_ * a4.w)};
            const float du = dB_ * uB_;
            h4.x = h4.x * e.x + du * BB_.x;
            h4.y = h4.y * e.y + du * BB_.y;
            h4.z = h4.z * e.z + du * BB_.z;
            h4.w = h4.w * e.w + du * BB_.w;
            sumd += dB_;
        }
        dA_ = dC_; uA_ = uC_; BA_ = BC_;
        dB_ = dD_; uB_ = uD_; BB_ = BD_;
    }

    const int pi = ((b * NCHUNK + k) * DI + c) * 16 + nq;
    const float4 P4 = {__expf(a4.x * sumd), __expf(a4.y * sumd),
                       __expf(a4.z * sumd), __expf(a4.w * sumd)};
    *(float4*)(P + pi) = P4;
    *(float4*)(Q + pi) = h4;
}

__global__ __launch_bounds__(256) void scan_p2(
    const float* __restrict__ P, const float* __restrict__ Q,
    float* __restrict__ HS)
{
    const int t  = blockIdx.x * 256 + threadIdx.x;   // 32768
    const int nq = (t & 3) << 2;
    const int c  = (t >> 2) & (DI - 1);
    const int b  = t >> 11;
    float4 hs = {0, 0, 0, 0};
    for (int k = 0; k < NCHUNK; ++k) {
        const int idx = ((b * NCHUNK + k) * DI + c) * 16 + nq;
        if (k > 0) {
            const int ip = idx - DI * 16;
            const float4 p4 = *(const float4*)(P + ip);
            const float4 q4 = *(const float4*)(Q + ip);
            hs.x = hs.x * p4.x + q4.x;
            hs.y = hs.y * p4.y + q4.y;
            hs.z = hs.z * p4.z + q4.z;
            hs.w = hs.w * p4.w + q4.w;
        }
        *(float4*)(HS + idx) = hs;
    }
}

__global__ __launch_bounds__(256) void scan_p3(
    const float* __restrict__ delta, const unsigned short* __restrict__ uch,
    const float* __restrict__ xdbl, const unsigned short* __restrict__ zuz,
    const float* __restrict__ A_log, const float* __restrict__ Dskip,
    const float* __restrict__ HS, unsigned short* __restrict__ y)
{
    const int tid = threadIdx.x;
    const int cg = blockIdx.x & 7, k = (blockIdx.x >> 3) & 15, b = blockIdx.x >> 7;
    const int c = (cg << 6) + (tid >> 2), nq = (tid & 3) << 2;

    const float4 al = *(const float4*)(A_log + c * DSTATE + nq);
    const float4 a4 = {-__expf(al.x), -__expf(al.y), -__expf(al.z), -__expf(al.w)};
    const float dsk = Dskip[c];

    const int pi = ((b * NCHUNK + k) * DI + c) * 16 + nq;
    float4 h4 = *(const float4*)(HS + pi);

    const int base = (b * LSEQ + k * CHUNK) * DI + c;
    const int xb   = (b * LSEQ + k * CHUNK) * 64 + DTRANK + nq;
    const int zb   = (b * LSEQ + k * CHUNK) * 1024 + c;

    float  dA_ = delta[base];
    float  uA_ = bf2f(uch[base]);
    float  zA_ = bf2f(zuz[zb]);
    float4 BA_ = *(const float4*)(xdbl + xb);
    float4 CA_ = *(const float4*)(xdbl + xb + DSTATE);
    float  dB_ = delta[base + DI];
    float  uB_ = bf2f(uch[base + DI]);
    float  zB_ = bf2f(zuz[zb + 1024]);
    float4 BB_ = *(const float4*)(xdbl + xb + 64);
    float4 CB_ = *(const float4*)(xdbl + xb + 64 + DSTATE);

    for (int l = 0; l < CHUNK; l += 2) {
        const int lc = (l + 2 < CHUNK) ? (l + 2) : (CHUNK - 2);
        const int o2 = base + lc * DI;
        const int x2 = xb + lc * 64;
        const int z2 = zb + lc * 1024;
        const float  dC_ = delta[o2];
        const float  dD_ = delta[o2 + DI];
        const float  uC_ = bf2f(uch[o2]);
        const float  uD_ = bf2f(uch[o2 + DI]);
        const float  zC_ = bf2f(zuz[z2]);
        const float  zD_ = bf2f(zuz[z2 + 1024]);
        const float4 BC_ = *(const float4*)(xdbl + x2);
        const float4 CC_ = *(const float4*)(xdbl + x2 + DSTATE);
        const float4 BD_ = *(const float4*)(xdbl + x2 + 64);
        const float4 CD_ = *(const float4*)(xdbl + x2 + 64 + DSTATE);

        {
            const float4 e = {__expf(dA_ * a4.x), __expf(dA_ * a4.y),
                              __expf(dA_ * a4.z), __expf(dA_ * a4.w)};
            const float du = dA_ * uA_;
            h4.x = h4.x * e.x + du * BA_.x;
            h4.y = h4.y * e.y + du * BA_.y;
            h4.z = h4.z * e.z + du * BA_.z;
            h4.w = h4.w * e.w + du * BA_.w;
            float yp = h4.x * CA_.x + h4.y * CA_.y + h4.z * CA_.z + h4.w * CA_.w;
            yp += __shfl_xor(yp, 1);
            yp += __shfl_xor(yp, 2);
            if ((tid & 3) == 0) {
                const float sg = 1.0f / (1.0f + __expf(-zA_));
                y[base + l * DI] = f2bf((yp + uA_ * dsk) * (zA_ * sg));
            }
        }
        {
            const float4 e = {__expf(dB_ * a4.x), __expf(dB_ * a4.y),
                              __expf(dB_ * a4.z), __expf(dB_ * a4.w)};
            const float du = dB_ * uB_;
            h4.x = h4.x * e.x + du * BB_.x;
            h4.y = h4.y * e.y + du * BB_.y;
            h4.z = h4.z * e.z + du * BB_.z;
            h4.w = h4.w * e.w + du * BB_.w;
            float yp = h4.x * CB_.x + h4.y * CB_.y + h4.z * CB_.z + h4.w * CB_.w;
            yp += __shfl_xor(yp, 1);
            yp += __shfl_xor(yp, 2);
            if ((tid & 3) == 0) {
                const float sg = 1.0f / (1.0f + __expf(-zB_));
                y[base + (l + 1) * DI] = f2bf((yp + uB_ * dsk) * (zB_ * sg));
            }
        }
        dA_ = dC_; uA_ = uC_; zA_ = zC_; BA_ = BC_; CA_ = CC_;
        dB_ = dD_; uB_ = uD_; zB_ = zD_; BB_ = BD_; CB_ = CD_;
    }
}

// ---------------------------------------------------------------------------
// LayerNorm over rows of 256; optional f32 and/or bf16 outputs.
// ---------------------------------------------------------------------------
__global__ __launch_bounds__(256) void layernorm256_kernel(
    const float* __restrict__ in, const float* __restrict__ g,
    const float* __restrict__ b, float* __restrict__ out,
    unsigned short* __restrict__ out16)
{
    const int wave = threadIdx.x >> 6;
    const int lane = threadIdx.x & 63;
    const int row  = blockIdx.x * 4 + wave;

    const float4 v = ((const float4*)(in + (size_t)row * DM))[lane];
    float s  = v.x + v.y + v.z + v.w;
    float sq = v.x * v.x + v.y * v.y + v.z * v.z + v.w * v.w;
    #pragma unroll
    for (int o = 1; o < 64; o <<= 1) {
        s  += __shfl_xor(s, o);
        sq += __shfl_xor(sq, o);
    }
    const float mu  = s * (1.0f / 256.0f);
    const float var = sq * (1.0f / 256.0f) - mu * mu;
    const float rs  = rsqrtf(var + 1e-12f);

    const float4 gg = ((const float4*)g)[lane];
    const float4 bb = ((const float4*)b)[lane];
    float4 o4;
    o4.x = (v.x - mu) * rs * gg.x + bb.x;
    o4.y = (v.y - mu) * rs * gg.y + bb.y;
    o4.z = (v.z - mu) * rs * gg.z + bb.z;
    o4.w = (v.w - mu) * rs * gg.w + bb.w;
    if (out)
        ((float4*)(out + (size_t)row * DM))[lane] = o4;
    if (out16) {
        uint2 p;
        p.x = (unsigned int)f2bf(o4.x) | ((unsigned int)f2bf(o4.y) << 16);
        p.y = (unsigned int)f2bf(o4.z) | ((unsigned int)f2bf(o4.w) << 16);
        *(uint2*)(out16 + (size_t)row * DM + lane * 4) = p;
    }
}

// ---------------------------------------------------------------------------
extern "C" void kernel_launch(void* const* d_in, const int* in_sizes, int n_in,
                              void* d_out, int out_size, void* d_ws, size_t ws_size,
                              hipStream_t stream)
{
    const float* x          = (const float*)d_in[0];
    const float* in_proj_w  = (const float*)d_in[1];
    const float* conv_w     = (const float*)d_in[2];
    const float* conv_b     = (const float*)d_in[3];
    const float* x_proj_w   = (const float*)d_in[4];
    const float* dt_proj_w  = (const float*)d_in[5];
    const float* dt_proj_b  = (const float*)d_in[6];
    const float* A_log      = (const float*)d_in[7];
    const float* Dskip      = (const float*)d_in[8];
    const float* out_proj_w = (const float*)d_in[9];
    const float* ln1_g      = (const float*)d_in[10];
    const float* ln1_b      = (const float*)d_in[11];
    const float* w1         = (const float*)d_in[12];
    const float* b1         = (const float*)d_in[13];
    const float* w2         = (const float*)d_in[14];
    const float* b2         = (const float*)d_in[15];
    const float* ln2_g      = (const float*)d_in[16];
    const float* ln2_b      = (const float*)d_in[17];
    float* out = (float*)d_out;
    char*  ws8 = (char*)d_ws;

    const size_t Mi = 1048576;
    unsigned short* bufUZ  = (unsigned short*)(ws8);
    unsigned short* bufUCh = (unsigned short*)(ws8 + 64 * Mi);
    float*          bufXD  = (float*)(ws8 + 96 * Mi);
    float*          bufDel = (float*)(ws8 + 104 * Mi);
    float*          bufP   = (float*)(ws8 + 168 * Mi);
    float*          bufQ   = (float*)(ws8 + 176 * Mi);
    float*          bufHS  = (float*)(ws8 + 184 * Mi);
    unsigned short* wb     = (unsigned short*)(ws8 + 192 * Mi);

    float*          bufM   = (float*)(ws8);                      // over uz lo
    float*          bufF2  = (float*)(ws8 + 32 * Mi);            // over uz hi
    unsigned short* bufFF  = (unsigned short*)(ws8 + 104 * Mi);  // over delta
    unsigned short* bufH1h = (unsigned short*)(ws8 + 168 * Mi);  // over P,Q
    unsigned short* bufY   = bufUCh;

    unsigned short* wInP16 = wb;
    unsigned short* wXP16  = wb + 262144;
    unsigned short* wOP16  = wb + 286720;
    unsigned short* wW116  = wb + 417792;
    unsigned short* wW216  = wb + 679936;

    unsigned short* x16 = (unsigned short*)d_out;

    const dim3 blk(256);
    const int MT = S_TOTAL / 128;   // 256 row tiles

    // 0) cast x + weights to bf16
    convert_kernel<<<dim3(36448), blk, 0, stream>>>(
        x, in_proj_w, x_proj_w, out_proj_w, w1, w2, x16, wb);

    // 1) in_proj (merged u|z) -> uz bf16 [S,1024]
    gemm_bf16<EPI_NONE, true><<<dim3(8, MT), blk, 0, stream>>>(
        x16, DM, wInP16, DM, nullptr, nullptr, 0, bufUZ, 1024, 1024, DM, 1023);

    // 2) depthwise causal conv + SiLU -> uch bf16
    conv_silu_kernel<<<dim3(S_TOTAL * 64 / 256), blk, 0, stream>>>(
        bufUZ, conv_w, conv_b, bufUCh);

    // 3) x_proj -> x_dbl f32 [S,64] (48 valid cols)
    gemm_bf16<EPI_NONE, false><<<dim3(1, MT), blk, 0, stream>>>(
        bufUCh, DI, wXP16, DI, nullptr, nullptr, 0, bufXD, 64, 64, DI, 47);

    // 4) dt_proj + softplus -> delta f32
    dt_kernel<<<dim3(S_TOTAL * 128 / 256), blk, 0, stream>>>(
        bufXD, dt_proj_w, dt_proj_b, bufDel);

    // 5) chunked selective scan -> y bf16 (in place over uch)
    scan_p1<<<dim3(NBATCH * NCHUNK * 8), blk, 0, stream>>>(
        bufDel, bufUCh, bufXD, A_log, bufP, bufQ);
    scan_p2<<<dim3(NBATCH * DI * 4 / 256), blk, 0, stream>>>(
        bufP, bufQ, bufHS);
    scan_p3<<<dim3(NBATCH * NCHUNK * 8), blk, 0, stream>>>(
        bufDel, bufUCh, bufXD, bufUZ + 512, A_log, Dskip, bufHS, bufY);

    // 6) out_proj + residual x (bf16) -> M f32 (pre-LN1)
    gemm_bf16<EPI_RESID16, false><<<dim3(2, MT), blk, 0, stream>>>(
        bufY, DI, wOP16, DI, nullptr, x16, DM, bufM, DM, 256, DI, 255);

    // 7) LN1 -> h1 bf16 only
    layernorm256_kernel<<<dim3(S_TOTAL / 4), blk, 0, stream>>>(
        bufM, ln1_g, ln1_b, nullptr, bufH1h);

    // 8) ff1: gelu(h1 @ w1^T + b1) -> FF bf16
    gemm_bf16<EPI_GELU_BIAS, true><<<dim3(8, MT), blk, 0, stream>>>(
        bufH1h, DM, wW116, DM, b1, nullptr, 0, bufFF, 1024, 1024, DM, 1023);

    // 9) ff2 + b2 + h1 (bf16 resid) -> F2 f32 (pre-LN2)
    gemm_bf16<EPI_BIAS_RESID16, false><<<dim3(2, MT), blk, 0, stream>>>(
        bufFF, 1024, wW216, 1024, b2, bufH1h, DM, bufF2, DM, 256, 1024, 255);

    // 10) LN2 -> out
    layernorm256_kernel<<<dim3(S_TOTAL / 4), blk, 0, stream>>>(
        bufF2, ln2_g, ln2_b, out, nullptr);
}

// Round 6
// 647.671 us; speedup vs baseline: 1.1943x; 1.1127x over previous
//
#include <hip/hip_runtime.h>
#include <cmath>

#define S_TOTAL 32768   // BATCH*SEQ
#define LSEQ    2048
#define NBATCH  16
#define DM      256
#define DI      512
#define DSTATE  16
#define DTRANK  16
#define NCHUNK  16
#define CHUNK   128     // LSEQ / NCHUNK

typedef __attribute__((ext_vector_type(8))) short short8;
typedef __attribute__((ext_vector_type(4))) float f32x4;

__device__ __forceinline__ unsigned short f2bf(float f) {
    union { float f; unsigned int u; } v; v.f = f;
    const unsigned int r = v.u + 0x7fffu + ((v.u >> 16) & 1u);
    return (unsigned short)(r >> 16);
}
__device__ __forceinline__ float bf2f(unsigned short h) {
    union { unsigned int u; float f; } v; v.u = ((unsigned int)h) << 16;
    return v.f;
}
__device__ __forceinline__ float gelu_exact(float x) {
    return 0.5f * x * (1.0f + erff(x * 0.70710678118654752440f));
}
// fast softplus: max(x,0) + log(1 + exp(-|x|)); HW v_exp/v_log, ~1e-6 rel err
__device__ __forceinline__ float softplus_fast(float x) {
    return fmaxf(x, 0.0f) + __logf(1.0f + __expf(-fabsf(x)));
}

enum { EPI_NONE = 0, EPI_GELU_BIAS = 1, EPI_RESID16 = 2, EPI_BIAS_RESID16 = 3 };

// ---------------------------------------------------------------------------
// bf16 MFMA GEMM: C[M,N] = epi(A[M,K](bf16) @ W[N,K](bf16)^T)
// 128x128 tile, BK=32, 4 waves, 16x16x32 MFMA. LDS = 32 KB -> 4 blocks/CU.
// Counted vmcnt(4) + raw s_barrier (prefetch loads stay in flight).
// LDS swizzle: slot ^= (row&3)^((row>>2)&3), applied on BOTH the global
// source (pre-swizzle) and the ds_read -> 2-way banks (free).
// ---------------------------------------------------------------------------
template <int EPI, bool OUTBF>
__global__ __launch_bounds__(256, 4) void gemm_bf16(
    const unsigned short* __restrict__ A, int lda,
    const unsigned short* __restrict__ W, int ldw,
    const float* __restrict__ bias,
    const unsigned short* __restrict__ resid, int ldr,
    void* __restrict__ Cout, int ldc, int nstore,
    int K, int nclampW)
{
    __shared__ unsigned short lds[2][2][4096];   // [buf][A/W][128*32] = 32 KB

    const int tid = threadIdx.x;
    const int w = tid >> 6, l = tid & 63;
    const int brow = blockIdx.y * 128, bcol = blockIdx.x * 128;
    const int wr = w >> 1, wc = w & 1;
    const int lr = l & 15, lh = l >> 4;

    f32x4 acc[4][4];
    #pragma unroll
    for (int m = 0; m < 4; ++m)
        #pragma unroll
        for (int n = 0; n < 4; ++n)
            acc[m][n] = f32x4{0.f, 0.f, 0.f, 0.f};

    auto stage = [&](int buf, int k0) {
        // linear LDS dest (lane*16B); global source pre-swizzled
        const int gslot = (l & 3) ^ ((l >> 2) & 3) ^ ((l >> 4) & 3);
        #pragma unroll
        for (int i = 0; i < 2; ++i) {
            const int row = i * 64 + w * 16 + (l >> 2);
            {
                const unsigned short* g =
                    A + (size_t)(brow + row) * lda + k0 + gslot * 8;
                const unsigned short* lp = &lds[buf][0][i * 2048 + w * 512];
                __builtin_amdgcn_global_load_lds(
                    (const __attribute__((address_space(1))) void*)g,
                    (__attribute__((address_space(3))) void*)lp, 16, 0, 0);
            }
            {
                int grow = bcol + row; if (grow > nclampW) grow = nclampW;
                const unsigned short* g =
                    W + (size_t)grow * ldw + k0 + gslot * 8;
                const unsigned short* lp = &lds[buf][1][i * 2048 + w * 512];
                __builtin_amdgcn_global_load_lds(
                    (const __attribute__((address_space(1))) void*)g,
                    (__attribute__((address_space(3))) void*)lp, 16, 0, 0);
            }
        }
    };

    stage(0, 0);                 // 4 VMEM ops per lane in flight

    const int nkt = K >> 5;
    for (int t = 0; t < nkt; ++t) {
        if (t + 1 < nkt) {
            stage((t + 1) & 1, (t + 1) << 5);   // +4 in flight
            __builtin_amdgcn_sched_barrier(0);
            asm volatile("s_waitcnt vmcnt(4)" ::: "memory");   // buf t landed
        } else {
            __builtin_amdgcn_sched_barrier(0);
            asm volatile("s_waitcnt vmcnt(0)" ::: "memory");
        }
        __builtin_amdgcn_s_barrier();          // all waves: buf[t] ready
        __builtin_amdgcn_sched_barrier(0);

        const unsigned short* la = &lds[t & 1][0][0];
        const unsigned short* lb = &lds[t & 1][1][0];
        short8 af[4], bw[4];
        #pragma unroll
        for (int m = 0; m < 4; ++m) {
            const int row = wr * 64 + m * 16 + lr;
            const int slot = lh ^ (row & 3) ^ ((row >> 2) & 3);
            af[m] = *(const short8*)(la + row * 32 + slot * 8);
        }
        #pragma unroll
        for (int n = 0; n < 4; ++n) {
            const int row = wc * 64 + n * 16 + lr;
            const int slot = lh ^ (row & 3) ^ ((row >> 2) & 3);
            bw[n] = *(const short8*)(lb + row * 32 + slot * 8);
        }
        #pragma unroll
        for (int m = 0; m < 4; ++m)
            #pragma unroll
            for (int n = 0; n < 4; ++n)
                acc[m][n] = __builtin_amdgcn_mfma_f32_16x16x32_bf16(
                    af[m], bw[n], acc[m][n], 0, 0, 0);

        __builtin_amdgcn_sched_barrier(0);
        asm volatile("s_waitcnt lgkmcnt(0)" ::: "memory");
        __builtin_amdgcn_s_barrier();          // safe to overwrite buf[t]
        __builtin_amdgcn_sched_barrier(0);
    }

    #pragma unroll
    for (int m = 0; m < 4; ++m) {
        #pragma unroll
        for (int j = 0; j < 4; ++j) {
            const int rg = brow + wr * 64 + m * 16 + lh * 4 + j;
            #pragma unroll
            for (int n = 0; n < 4; ++n) {
                const int cg = bcol + wc * 64 + n * 16 + lr;
                if (cg < nstore) {
                    float v = acc[m][n][j];
                    if (EPI == EPI_GELU_BIAS) {
                        v = gelu_exact(v + bias[cg]);
                    } else if (EPI == EPI_RESID16) {
                        v += bf2f(resid[(size_t)rg * ldr + cg]);
                    } else if (EPI == EPI_BIAS_RESID16) {
                        v += bias[cg] + bf2f(resid[(size_t)rg * ldr + cg]);
                    }
                    if (OUTBF)
                        ((unsigned short*)Cout)[(size_t)rg * ldc + cg] = f2bf(v);
                    else
                        ((float*)Cout)[(size_t)rg * ldc + cg] = v;
                }
            }
        }
    }
}

// ---------------------------------------------------------------------------
// Convert x (f32 -> bf16) and the 5 GEMM weight matrices.
// ---------------------------------------------------------------------------
__global__ __launch_bounds__(256) void convert_kernel(
    const float* __restrict__ x,   const float* __restrict__ win,
    const float* __restrict__ wxp, const float* __restrict__ wop,
    const float* __restrict__ w1,  const float* __restrict__ w2,
    unsigned short* __restrict__ x16, unsigned short* __restrict__ wb)
{
    int idx = blockIdx.x * 256 + threadIdx.x;
    const int NX = S_TOTAL * DM;                         // 8388608
    if (idx < NX) { x16[idx] = f2bf(x[idx]); return; }
    idx -= NX;
    if (idx < 262144) { wb[idx] = f2bf(win[idx]); return; }
    idx -= 262144;
    if (idx < 24576)  { wb[262144 + idx] = f2bf(wxp[idx]); return; }
    idx -= 24576;
    if (idx < 131072) { wb[286720 + idx] = f2bf(wop[idx]); return; }
    idx -= 131072;
    if (idx < 262144) { wb[417792 + idx] = f2bf(w1[idx]); return; }
    idx -= 262144;
    if (idx < 262144) { wb[679936 + idx] = f2bf(w2[idx]); return; }
}

// ---------------------------------------------------------------------------
// Depthwise causal conv1d (width 4, bf16 in from uz[:, 0:512]) + bias + SiLU.
// ---------------------------------------------------------------------------
__global__ __launch_bounds__(256) void conv_silu_kernel(
    const unsigned short* __restrict__ uz, const float* __restrict__ cw,
    const float* __restrict__ cb, unsigned short* __restrict__ uch)
{
    const int idx = blockIdx.x * 256 + threadIdx.x;   // < S_TOTAL*64
    const int g = idx & 63;
    const int s = idx >> 6;
    const int l = s & (LSEQ - 1);
    const int c0 = g * 8;

    float acc[8];
    float4 cwv[8];
    #pragma unroll
    for (int j = 0; j < 8; ++j) {
        acc[j] = cb[c0 + j];
        cwv[j] = *(const float4*)(cw + (c0 + j) * 4);
    }
    #pragma unroll
    for (int t = 0; t < 4; ++t) {
        const int lt = l - 3 + t;
        if (lt >= 0) {
            const short8 uv = *(const short8*)(uz + (s - 3 + t) * 1024 + c0);
            #pragma unroll
            for (int j = 0; j < 8; ++j) {
                const float wt = (t == 0) ? cwv[j].x : (t == 1) ? cwv[j].y
                               : (t == 2) ? cwv[j].z : cwv[j].w;
                acc[j] += bf2f((unsigned short)uv[j]) * wt;
            }
        }
    }
    short8 ob;
    #pragma unroll
    for (int j = 0; j < 8; ++j) {
        const float sig = 1.0f / (1.0f + __expf(-acc[j]));
        ob[j] = (short)f2bf(acc[j] * sig);
    }
    *(short8*)(uch + s * DI + c0) = ob;
}

// ---------------------------------------------------------------------------
// Chunked selective scan (3 passes), v3: dt_proj+softplus FUSED.
// Channel c's 4 lanes hold dtw[c, nq:nq+4]; per step: quad-dot via 2
// shfl_xor, fast softplus -> delta on the fly. No delta buffer at all.
// ---------------------------------------------------------------------------
__global__ __launch_bounds__(256) void scan_p1(
    const unsigned short* __restrict__ uch, const float* __restrict__ xdbl,
    const float* __restrict__ dtw, const float* __restrict__ dtb,
    const float* __restrict__ A_log,
    float* __restrict__ P, float* __restrict__ Q)
{
    const int tid = threadIdx.x;
    const int cg = blockIdx.x & 7, k = (blockIdx.x >> 3) & 15, b = blockIdx.x >> 7;
    const int c = (cg << 6) + (tid >> 2), nq = (tid & 3) << 2;

    const float4 al = *(const float4*)(A_log + c * DSTATE + nq);
    const float4 a4 = {-__expf(al.x), -__expf(al.y), -__expf(al.z), -__expf(al.w)};
    const float4 dw4 = *(const float4*)(dtw + c * DTRANK + nq);
    const float dtbc = dtb[c];

    float4 h4 = {0, 0, 0, 0};
    float sumd = 0.f;

    const int base = (b * LSEQ + k * CHUNK) * DI + c;
    const int xb   = (b * LSEQ + k * CHUNK) * 64 + nq;   // dt quad at col nq

    float  uA_ = bf2f(uch[base]);
    float4 TA_ = *(const float4*)(xdbl + xb);
    float4 BA_ = *(const float4*)(xdbl + xb + DTRANK);
    float  uB_ = bf2f(uch[base + DI]);
    float4 TB_ = *(const float4*)(xdbl + xb + 64);
    float4 BB_ = *(const float4*)(xdbl + xb + 64 + DTRANK);

    for (int l = 0; l < CHUNK; l += 2) {
        const int lc = (l + 2 < CHUNK) ? (l + 2) : (CHUNK - 2);
        const int o2 = base + lc * DI;
        const int x2 = xb + lc * 64;
        const float  uC_ = bf2f(uch[o2]);
        const float  uD_ = bf2f(uch[o2 + DI]);
        const float4 TC_ = *(const float4*)(xdbl + x2);
        const float4 BC_ = *(const float4*)(xdbl + x2 + DTRANK);
        const float4 TD_ = *(const float4*)(xdbl + x2 + 64);
        const float4 BD_ = *(const float4*)(xdbl + x2 + 64 + DTRANK);

        {
            float pd = TA_.x * dw4.x + TA_.y * dw4.y + TA_.z * dw4.z + TA_.w * dw4.w;
            pd += __shfl_xor(pd, 1);
            pd += __shfl_xor(pd, 2);
            const float d = softplus_fast(pd + dtbc);
            const float4 e = {__expf(d * a4.x), __expf(d * a4.y),
                              __expf(d * a4.z), __expf(d * a4.w)};
            const float du = d * uA_;
            h4.x = h4.x * e.x + du * BA_.x;
            h4.y = h4.y * e.y + du * BA_.y;
            h4.z = h4.z * e.z + du * BA_.z;
            h4.w = h4.w * e.w + du * BA_.w;
            sumd += d;
        }
        {
            float pd = TB_.x * dw4.x + TB_.y * dw4.y + TB_.z * dw4.z + TB_.w * dw4.w;
            pd += __shfl_xor(pd, 1);
            pd += __shfl_xor(pd, 2);
            const float d = softplus_fast(pd + dtbc);
            const float4 e = {__expf(d * a4.x), __expf(d * a4.y),
                              __expf(d * a4.z), __expf(d * a4.w)};
            const float du = d * uB_;
            h4.x = h4.x * e.x + du * BB_.x;
            h4.y = h4.y * e.y + du * BB_.y;
            h4.z = h4.z * e.z + du * BB_.z;
            h4.w = h4.w * e.w + du * BB_.w;
            sumd += d;
        }
        uA_ = uC_; TA_ = TC_; BA_ = BC_;
        uB_ = uD_; TB_ = TD_; BB_ = BD_;
    }

    const int pi = ((b * NCHUNK + k) * DI + c) * 16 + nq;
    const float4 P4 = {__expf(a4.x * sumd), __expf(a4.y * sumd),
                       __expf(a4.z * sumd), __expf(a4.w * sumd)};
    *(float4*)(P + pi) = P4;
    *(float4*)(Q + pi) = h4;
}

__global__ __launch_bounds__(256) void scan_p2(
    const float* __restrict__ P, const float* __restrict__ Q,
    float* __restrict__ HS)
{
    const int t  = blockIdx.x * 256 + threadIdx.x;   // 32768
    const int nq = (t & 3) << 2;
    const int c  = (t >> 2) & (DI - 1);
    const int b  = t >> 11;
    float4 hs = {0, 0, 0, 0};
    for (int k = 0; k < NCHUNK; ++k) {
        const int idx = ((b * NCHUNK + k) * DI + c) * 16 + nq;
        if (k > 0) {
            const int ip = idx - DI * 16;
            const float4 p4 = *(const float4*)(P + ip);
            const float4 q4 = *(const float4*)(Q + ip);
            hs.x = hs.x * p4.x + q4.x;
            hs.y = hs.y * p4.y + q4.y;
            hs.z = hs.z * p4.z + q4.z;
            hs.w = hs.w * p4.w + q4.w;
        }
        *(float4*)(HS + idx) = hs;
    }
}

__global__ __launch_bounds__(256) void scan_p3(
    const unsigned short* __restrict__ uch, const float* __restrict__ xdbl,
    const float* __restrict__ dtw, const float* __restrict__ dtb,
    const unsigned short* __restrict__ zuz,
    const float* __restrict__ A_log, const float* __restrict__ Dskip,
    const float* __restrict__ HS, unsigned short* __restrict__ y)
{
    const int tid = threadIdx.x;
    const int cg = blockIdx.x & 7, k = (blockIdx.x >> 3) & 15, b = blockIdx.x >> 7;
    const int c = (cg << 6) + (tid >> 2), nq = (tid & 3) << 2;

    const float4 al = *(const float4*)(A_log + c * DSTATE + nq);
    const float4 a4 = {-__expf(al.x), -__expf(al.y), -__expf(al.z), -__expf(al.w)};
    const float4 dw4 = *(const float4*)(dtw + c * DTRANK + nq);
    const float dtbc = dtb[c];
    const float dsk = Dskip[c];

    const int pi = ((b * NCHUNK + k) * DI + c) * 16 + nq;
    float4 h4 = *(const float4*)(HS + pi);

    const int base = (b * LSEQ + k * CHUNK) * DI + c;
    const int xb   = (b * LSEQ + k * CHUNK) * 64 + nq;
    const int zb   = (b * LSEQ + k * CHUNK) * 1024 + c;

    float  uA_ = bf2f(uch[base]);
    float  zA_ = bf2f(zuz[zb]);
    float4 TA_ = *(const float4*)(xdbl + xb);
    float4 BA_ = *(const float4*)(xdbl + xb + DTRANK);
    float4 CA_ = *(const float4*)(xdbl + xb + 32);
    float  uB_ = bf2f(uch[base + DI]);
    float  zB_ = bf2f(zuz[zb + 1024]);
    float4 TB_ = *(const float4*)(xdbl + xb + 64);
    float4 BB_ = *(const float4*)(xdbl + xb + 64 + DTRANK);
    float4 CB_ = *(const float4*)(xdbl + xb + 64 + 32);

    for (int l = 0; l < CHUNK; l += 2) {
        const int lc = (l + 2 < CHUNK) ? (l + 2) : (CHUNK - 2);
        const int o2 = base + lc * DI;
        const int x2 = xb + lc * 64;
        const int z2 = zb + lc * 1024;
        const float  uC_ = bf2f(uch[o2]);
        const float  uD_ = bf2f(uch[o2 + DI]);
        const float  zC_ = bf2f(zuz[z2]);
        const float  zD_ = bf2f(zuz[z2 + 1024]);
        const float4 TC_ = *(const float4*)(xdbl + x2);
        const float4 BC_ = *(const float4*)(xdbl + x2 + DTRANK);
        const float4 CC_ = *(const float4*)(xdbl + x2 + 32);
        const float4 TD_ = *(const float4*)(xdbl + x2 + 64);
        const float4 BD_ = *(const float4*)(xdbl + x2 + 64 + DTRANK);
        const float4 CD_ = *(const float4*)(xdbl + x2 + 64 + 32);

        {
            float pd = TA_.x * dw4.x + TA_.y * dw4.y + TA_.z * dw4.z + TA_.w * dw4.w;
            pd += __shfl_xor(pd, 1);
            pd += __shfl_xor(pd, 2);
            const float d = softplus_fast(pd + dtbc);
            const float4 e = {__expf(d * a4.x), __expf(d * a4.y),
                              __expf(d * a4.z), __expf(d * a4.w)};
            const float du = d * uA_;
            h4.x = h4.x * e.x + du * BA_.x;
            h4.y = h4.y * e.y + du * BA_.y;
            h4.z = h4.z * e.z + du * BA_.z;
            h4.w = h4.w * e.w + du * BA_.w;
            float yp = h4.x * CA_.x + h4.y * CA_.y + h4.z * CA_.z + h4.w * CA_.w;
            yp += __shfl_xor(yp, 1);
            yp += __shfl_xor(yp, 2);
            if ((tid & 3) == 0) {
                const float sg = 1.0f / (1.0f + __expf(-zA_));
                y[base + l * DI] = f2bf((yp + uA_ * dsk) * (zA_ * sg));
            }
        }
        {
            float pd = TB_.x * dw4.x + TB_.y * dw4.y + TB_.z * dw4.z + TB_.w * dw4.w;
            pd += __shfl_xor(pd, 1);
            pd += __shfl_xor(pd, 2);
            const float d = softplus_fast(pd + dtbc);
            const float4 e = {__expf(d * a4.x), __expf(d * a4.y),
                              __expf(d * a4.z), __expf(d * a4.w)};
            const float du = d * uB_;
            h4.x = h4.x * e.x + du * BB_.x;
            h4.y = h4.y * e.y + du * BB_.y;
            h4.z = h4.z * e.z + du * BB_.z;
            h4.w = h4.w * e.w + du * BB_.w;
            float yp = h4.x * CB_.x + h4.y * CB_.y + h4.z * CB_.z + h4.w * CB_.w;
            yp += __shfl_xor(yp, 1);
            yp += __shfl_xor(yp, 2);
            if ((tid & 3) == 0) {
                const float sg = 1.0f / (1.0f + __expf(-zB_));
                y[base + (l + 1) * DI] = f2bf((yp + uB_ * dsk) * (zB_ * sg));
            }
        }
        uA_ = uC_; zA_ = zC_; TA_ = TC_; BA_ = BC_; CA_ = CC_;
        uB_ = uD_; zB_ = zD_; TB_ = TD_; BB_ = BD_; CB_ = CD_;
    }
}

// ---------------------------------------------------------------------------
// LayerNorm over rows of 256; optional f32 and/or bf16 outputs.
// ---------------------------------------------------------------------------
__global__ __launch_bounds__(256) void layernorm256_kernel(
    const float* __restrict__ in, const float* __restrict__ g,
    const float* __restrict__ b, float* __restrict__ out,
    unsigned short* __restrict__ out16)
{
    const int wave = threadIdx.x >> 6;
    const int lane = threadIdx.x & 63;
    const int row  = blockIdx.x * 4 + wave;

    const float4 v = ((const float4*)(in + (size_t)row * DM))[lane];
    float s  = v.x + v.y + v.z + v.w;
    float sq = v.x * v.x + v.y * v.y + v.z * v.z + v.w * v.w;
    #pragma unroll
    for (int o = 1; o < 64; o <<= 1) {
        s  += __shfl_xor(s, o);
        sq += __shfl_xor(sq, o);
    }
    const float mu  = s * (1.0f / 256.0f);
    const float var = sq * (1.0f / 256.0f) - mu * mu;
    const float rs  = rsqrtf(var + 1e-12f);

    const float4 gg = ((const float4*)g)[lane];
    const float4 bb = ((const float4*)b)[lane];
    float4 o4;
    o4.x = (v.x - mu) * rs * gg.x + bb.x;
    o4.y = (v.y - mu) * rs * gg.y + bb.y;
    o4.z = (v.z - mu) * rs * gg.z + bb.z;
    o4.w = (v.w - mu) * rs * gg.w + bb.w;
    if (out)
        ((float4*)(out + (size_t)row * DM))[lane] = o4;
    if (out16) {
        uint2 p;
        p.x = (unsigned int)f2bf(o4.x) | ((unsigned int)f2bf(o4.y) << 16);
        p.y = (unsigned int)f2bf(o4.z) | ((unsigned int)f2bf(o4.w) << 16);
        *(uint2*)(out16 + (size_t)row * DM + lane * 4) = p;
    }
}

// ---------------------------------------------------------------------------
extern "C" void kernel_launch(void* const* d_in, const int* in_sizes, int n_in,
                              void* d_out, int out_size, void* d_ws, size_t ws_size,
                              hipStream_t stream)
{
    const float* x          = (const float*)d_in[0];
    const float* in_proj_w  = (const float*)d_in[1];
    const float* conv_w     = (const float*)d_in[2];
    const float* conv_b     = (const float*)d_in[3];
    const float* x_proj_w   = (const float*)d_in[4];
    const float* dt_proj_w  = (const float*)d_in[5];
    const float* dt_proj_b  = (const float*)d_in[6];
    const float* A_log      = (const float*)d_in[7];
    const float* Dskip      = (const float*)d_in[8];
    const float* out_proj_w = (const float*)d_in[9];
    const float* ln1_g      = (const float*)d_in[10];
    const float* ln1_b      = (const float*)d_in[11];
    const float* w1         = (const float*)d_in[12];
    const float* b1         = (const float*)d_in[13];
    const float* w2         = (const float*)d_in[14];
    const float* b2         = (const float*)d_in[15];
    const float* ln2_g      = (const float*)d_in[16];
    const float* ln2_b      = (const float*)d_in[17];
    float* out = (float*)d_out;
    char*  ws8 = (char*)d_ws;

    const size_t Mi = 1048576;
    // Workspace map (byte offsets):
    //  [  0, 64Mi): uz bf16 [S,1024]    -> after p3: M f32 [0,32Mi), F2 f32 [32,64Mi)
    //  [ 64, 96Mi): uch bf16 [S,512]    -> y bf16 in-place
    //  [ 96,104Mi): x_dbl f32 [S,64]
    //  [104,168Mi): FF bf16 [S,1024] (ff hidden)
    //  [168,176Mi): P f32; [176,184Mi): Q f32   -> after p2: H1h bf16
    //  [184,192Mi): HS f32
    //  [192,194Mi): bf16 weights
    unsigned short* bufUZ  = (unsigned short*)(ws8);
    unsigned short* bufUCh = (unsigned short*)(ws8 + 64 * Mi);
    float*          bufXD  = (float*)(ws8 + 96 * Mi);
    unsigned short* bufFF  = (unsigned short*)(ws8 + 104 * Mi);
    float*          bufP   = (float*)(ws8 + 168 * Mi);
    float*          bufQ   = (float*)(ws8 + 176 * Mi);
    float*          bufHS  = (float*)(ws8 + 184 * Mi);
    unsigned short* wb     = (unsigned short*)(ws8 + 192 * Mi);

    float*          bufM   = (float*)(ws8);                      // over uz lo
    float*          bufF2  = (float*)(ws8 + 32 * Mi);            // over uz hi
    unsigned short* bufH1h = (unsigned short*)(ws8 + 168 * Mi);  // over P,Q
    unsigned short* bufY   = bufUCh;

    unsigned short* wInP16 = wb;
    unsigned short* wXP16  = wb + 262144;
    unsigned short* wOP16  = wb + 286720;
    unsigned short* wW116  = wb + 417792;
    unsigned short* wW216  = wb + 679936;

    unsigned short* x16 = (unsigned short*)d_out;

    const dim3 blk(256);
    const int MT = S_TOTAL / 128;   // 256 row tiles

    // 0) cast x + weights to bf16
    convert_kernel<<<dim3(36448), blk, 0, stream>>>(
        x, in_proj_w, x_proj_w, out_proj_w, w1, w2, x16, wb);

    // 1) in_proj (merged u|z) -> uz bf16 [S,1024]
    gemm_bf16<EPI_NONE, true><<<dim3(8, MT), blk, 0, stream>>>(
        x16, DM, wInP16, DM, nullptr, nullptr, 0, bufUZ, 1024, 1024, DM, 1023);

    // 2) depthwise causal conv + SiLU -> uch bf16
    conv_silu_kernel<<<dim3(S_TOTAL * 64 / 256), blk, 0, stream>>>(
        bufUZ, conv_w, conv_b, bufUCh);

    // 3) x_proj -> x_dbl f32 [S,64] (48 valid cols)
    gemm_bf16<EPI_NONE, false><<<dim3(1, MT), blk, 0, stream>>>(
        bufUCh, DI, wXP16, DI, nullptr, nullptr, 0, bufXD, 64, 64, DI, 47);

    // 4+5) chunked selective scan with fused dt_proj -> y bf16 (over uch)
    scan_p1<<<dim3(NBATCH * NCHUNK * 8), blk, 0, stream>>>(
        bufUCh, bufXD, dt_proj_w, dt_proj_b, A_log, bufP, bufQ);
    scan_p2<<<dim3(NBATCH * DI * 4 / 256), blk, 0, stream>>>(
        bufP, bufQ, bufHS);
    scan_p3<<<dim3(NBATCH * NCHUNK * 8), blk, 0, stream>>>(
        bufUCh, bufXD, dt_proj_w, dt_proj_b, bufUZ + 512, A_log, Dskip,
        bufHS, bufY);

    // 6) out_proj + residual x (bf16) -> M f32 (pre-LN1)
    gemm_bf16<EPI_RESID16, false><<<dim3(2, MT), blk, 0, stream>>>(
        bufY, DI, wOP16, DI, nullptr, x16, DM, bufM, DM, 256, DI, 255);

    // 7) LN1 -> h1 bf16 only
    layernorm256_kernel<<<dim3(S_TOTAL / 4), blk, 0, stream>>>(
        bufM, ln1_g, ln1_b, nullptr, bufH1h);

    // 8) ff1: gelu(h1 @ w1^T + b1) -> FF bf16
    gemm_bf16<EPI_GELU_BIAS, true><<<dim3(8, MT), blk, 0, stream>>>(
        bufH1h, DM, wW116, DM, b1, nullptr, 0, bufFF, 1024, 1024, DM, 1023);

    // 9) ff2 + b2 + h1 (bf16 resid) -> F2 f32 (pre-LN2)
    gemm_bf16<EPI_BIAS_RESID16, false><<<dim3(2, MT), blk, 0, stream>>>(
        bufFF, 1024, wW216, 1024, b2, bufH1h, DM, bufF2, DM, 256, 1024, 255);

    // 10) LN2 -> out
    layernorm256_kernel<<<dim3(S_TOTAL / 4), blk, 0, stream>>>(
        bufF2, ln2_g, ln2_b, out, nullptr);
}

// Round 7
// 566.167 us; speedup vs baseline: 1.3662x; 1.1440x over previous
//
#include <hip/hip_runtime.h>
#include <cmath>

#define S_TOTAL 32768   // BATCH*SEQ
#define LSEQ    2048
#define NBATCH  16
#define DM      256
#define DI      512
#define DSTATE  16
#define DTRANK  16
#define NCHUNK  32
#define CHUNK   64      // LSEQ / NCHUNK

typedef __attribute__((ext_vector_type(8))) short short8;
typedef __attribute__((ext_vector_type(4))) float f32x4;

__device__ __forceinline__ unsigned short f2bf(float f) {
    union { float f; unsigned int u; } v; v.f = f;
    const unsigned int r = v.u + 0x7fffu + ((v.u >> 16) & 1u);
    return (unsigned short)(r >> 16);
}
__device__ __forceinline__ float bf2f(unsigned short h) {
    union { unsigned int u; float f; } v; v.u = ((unsigned int)h) << 16;
    return v.f;
}
__device__ __forceinline__ float gelu_exact(float x) {
    return 0.5f * x * (1.0f + erff(x * 0.70710678118654752440f));
}
// fast softplus: max(x,0) + log(1 + exp(-|x|)); HW v_exp/v_log
__device__ __forceinline__ float softplus_fast(float x) {
    return fmaxf(x, 0.0f) + __logf(1.0f + __expf(-fabsf(x)));
}

enum { EPI_NONE = 0, EPI_GELU_BIAS = 1, EPI_RESID16 = 2, EPI_BIAS_RESID16 = 3,
       EPI_SOFTPLUS_BIAS = 4 };

// ---------------------------------------------------------------------------
// bf16 MFMA GEMM: C[M,N] = epi(A[M,K](bf16) @ W[N,K](bf16)^T)
// 128x128 tile, BK=32, 4 waves, 16x16x32 MFMA. LDS = 32 KB -> 4 blocks/CU.
// Counted vmcnt(4) + raw s_barrier (prefetch loads stay in flight).
// Optional aux bf16 output (first auxn cols) for x_proj's dt slice.
// ---------------------------------------------------------------------------
template <int EPI, bool OUTBF>
__global__ __launch_bounds__(256, 4) void gemm_bf16(
    const unsigned short* __restrict__ A, int lda,
    const unsigned short* __restrict__ W, int ldw,
    const float* __restrict__ bias,
    const unsigned short* __restrict__ resid, int ldr,
    void* __restrict__ Cout, int ldc, int nstore,
    int K, int nclampW,
    unsigned short* __restrict__ aux, int auxn)
{
    __shared__ unsigned short lds[2][2][4096];   // [buf][A/W][128*32] = 32 KB

    const int tid = threadIdx.x;
    const int w = tid >> 6, l = tid & 63;
    const int brow = blockIdx.y * 128, bcol = blockIdx.x * 128;
    const int wr = w >> 1, wc = w & 1;
    const int lr = l & 15, lh = l >> 4;

    f32x4 acc[4][4];
    #pragma unroll
    for (int m = 0; m < 4; ++m)
        #pragma unroll
        for (int n = 0; n < 4; ++n)
            acc[m][n] = f32x4{0.f, 0.f, 0.f, 0.f};

    auto stage = [&](int buf, int k0) {
        const int gslot = (l & 3) ^ ((l >> 2) & 3) ^ ((l >> 4) & 3);
        #pragma unroll
        for (int i = 0; i < 2; ++i) {
            const int row = i * 64 + w * 16 + (l >> 2);
            {
                const unsigned short* g =
                    A + (size_t)(brow + row) * lda + k0 + gslot * 8;
                const unsigned short* lp = &lds[buf][0][i * 2048 + w * 512];
                __builtin_amdgcn_global_load_lds(
                    (const __attribute__((address_space(1))) void*)g,
                    (__attribute__((address_space(3))) void*)lp, 16, 0, 0);
            }
            {
                int grow = bcol + row; if (grow > nclampW) grow = nclampW;
                const unsigned short* g =
                    W + (size_t)grow * ldw + k0 + gslot * 8;
                const unsigned short* lp = &lds[buf][1][i * 2048 + w * 512];
                __builtin_amdgcn_global_load_lds(
                    (const __attribute__((address_space(1))) void*)g,
                    (__attribute__((address_space(3))) void*)lp, 16, 0, 0);
            }
        }
    };

    stage(0, 0);

    const int nkt = K >> 5;
    for (int t = 0; t < nkt; ++t) {
        if (t + 1 < nkt) {
            stage((t + 1) & 1, (t + 1) << 5);
            __builtin_amdgcn_sched_barrier(0);
            asm volatile("s_waitcnt vmcnt(4)" ::: "memory");
        } else {
            __builtin_amdgcn_sched_barrier(0);
            asm volatile("s_waitcnt vmcnt(0)" ::: "memory");
        }
        __builtin_amdgcn_s_barrier();
        __builtin_amdgcn_sched_barrier(0);

        const unsigned short* la = &lds[t & 1][0][0];
        const unsigned short* lb = &lds[t & 1][1][0];
        short8 af[4], bw[4];
        #pragma unroll
        for (int m = 0; m < 4; ++m) {
            const int row = wr * 64 + m * 16 + lr;
            const int slot = lh ^ (row & 3) ^ ((row >> 2) & 3);
            af[m] = *(const short8*)(la + row * 32 + slot * 8);
        }
        #pragma unroll
        for (int n = 0; n < 4; ++n) {
            const int row = wc * 64 + n * 16 + lr;
            const int slot = lh ^ (row & 3) ^ ((row >> 2) & 3);
            bw[n] = *(const short8*)(lb + row * 32 + slot * 8);
        }
        #pragma unroll
        for (int m = 0; m < 4; ++m)
            #pragma unroll
            for (int n = 0; n < 4; ++n)
                acc[m][n] = __builtin_amdgcn_mfma_f32_16x16x32_bf16(
                    af[m], bw[n], acc[m][n], 0, 0, 0);

        __builtin_amdgcn_sched_barrier(0);
        asm volatile("s_waitcnt lgkmcnt(0)" ::: "memory");
        __builtin_amdgcn_s_barrier();
        __builtin_amdgcn_sched_barrier(0);
    }

    #pragma unroll
    for (int m = 0; m < 4; ++m) {
        #pragma unroll
        for (int j = 0; j < 4; ++j) {
            const int rg = brow + wr * 64 + m * 16 + lh * 4 + j;
            #pragma unroll
            for (int n = 0; n < 4; ++n) {
                const int cg = bcol + wc * 64 + n * 16 + lr;
                if (cg < nstore) {
                    float v = acc[m][n][j];
                    if (EPI == EPI_GELU_BIAS) {
                        v = gelu_exact(v + bias[cg]);
                    } else if (EPI == EPI_RESID16) {
                        v += bf2f(resid[(size_t)rg * ldr + cg]);
                    } else if (EPI == EPI_BIAS_RESID16) {
                        v += bias[cg] + bf2f(resid[(size_t)rg * ldr + cg]);
                    } else if (EPI == EPI_SOFTPLUS_BIAS) {
                        v = softplus_fast(v + bias[cg]);
                    }
                    if (OUTBF)
                        ((unsigned short*)Cout)[(size_t)rg * ldc + cg] = f2bf(v);
                    else
                        ((float*)Cout)[(size_t)rg * ldc + cg] = v;
                    if (aux && cg < auxn)
                        aux[(size_t)rg * auxn + cg] = f2bf(v);
                }
            }
        }
    }
}

// ---------------------------------------------------------------------------
// Convert x (f32 -> bf16), 5 GEMM weights, and zero-padded dtw [512,32].
// ---------------------------------------------------------------------------
__global__ __launch_bounds__(256) void convert_kernel(
    const float* __restrict__ x,   const float* __restrict__ win,
    const float* __restrict__ wxp, const float* __restrict__ wop,
    const float* __restrict__ w1,  const float* __restrict__ w2,
    const float* __restrict__ dtw,
    unsigned short* __restrict__ x16, unsigned short* __restrict__ wb)
{
    int idx = blockIdx.x * 256 + threadIdx.x;
    const int NX = S_TOTAL * DM;                         // 8388608
    if (idx < NX) { x16[idx] = f2bf(x[idx]); return; }
    idx -= NX;
    if (idx < 262144) { wb[idx] = f2bf(win[idx]); return; }
    idx -= 262144;
    if (idx < 24576)  { wb[262144 + idx] = f2bf(wxp[idx]); return; }
    idx -= 24576;
    if (idx < 131072) { wb[286720 + idx] = f2bf(wop[idx]); return; }
    idx -= 131072;
    if (idx < 262144) { wb[417792 + idx] = f2bf(w1[idx]); return; }
    idx -= 262144;
    if (idx < 262144) { wb[679936 + idx] = f2bf(w2[idx]); return; }
    idx -= 262144;
    if (idx < 16384) {
        const int r = idx >> 5, q = idx & 31;
        wb[942080 + idx] = (q < DTRANK) ? f2bf(dtw[r * DTRANK + q])
                                        : (unsigned short)0;
    }
}

// ---------------------------------------------------------------------------
// Depthwise causal conv1d (width 4, bf16 in from uz[:, 0:512]) + bias + SiLU.
// ---------------------------------------------------------------------------
__global__ __launch_bounds__(256) void conv_silu_kernel(
    const unsigned short* __restrict__ uz, const float* __restrict__ cw,
    const float* __restrict__ cb, unsigned short* __restrict__ uch)
{
    const int idx = blockIdx.x * 256 + threadIdx.x;   // < S_TOTAL*64
    const int g = idx & 63;
    const int s = idx >> 6;
    const int l = s & (LSEQ - 1);
    const int c0 = g * 8;

    float acc[8];
    float4 cwv[8];
    #pragma unroll
    for (int j = 0; j < 8; ++j) {
        acc[j] = cb[c0 + j];
        cwv[j] = *(const float4*)(cw + (c0 + j) * 4);
    }
    #pragma unroll
    for (int t = 0; t < 4; ++t) {
        const int lt = l - 3 + t;
        if (lt >= 0) {
            const short8 uv = *(const short8*)(uz + (s - 3 + t) * 1024 + c0);
            #pragma unroll
            for (int j = 0; j < 8; ++j) {
                const float wt = (t == 0) ? cwv[j].x : (t == 1) ? cwv[j].y
                               : (t == 2) ? cwv[j].z : cwv[j].w;
                acc[j] += bf2f((unsigned short)uv[j]) * wt;
            }
        }
    }
    short8 ob;
    #pragma unroll
    for (int j = 0; j < 8; ++j) {
        const float sig = 1.0f / (1.0f + __expf(-acc[j]));
        ob[j] = (short)f2bf(acc[j] * sig);
    }
    *(short8*)(uch + s * DI + c0) = ob;
}

// ---------------------------------------------------------------------------
// Chunked selective scan, v4: delta precomputed (bf16), 8 states/lane
// (2 lanes per channel, 32 channels/wave), pointer-bump ping-pong loop
// with unguarded distance-1 prefetch (1-row over-read lands in adjacent
// ws allocations and is never consumed).
// Grid: NBATCH * NCHUNK * 4 = 2048 blocks; CHUNK = 64.
// ---------------------------------------------------------------------------
__global__ __launch_bounds__(256) void scan_p1(
    const unsigned short* __restrict__ uch,
    const unsigned short* __restrict__ delh,
    const float* __restrict__ xdbl, const float* __restrict__ A_log,
    float* __restrict__ P, float* __restrict__ Q)
{
    const int tid = threadIdx.x;
    const int w = tid >> 6, lane = tid & 63;
    const int cgb = blockIdx.x & 3;
    const int k = (blockIdx.x >> 2) & (NCHUNK - 1);
    const int b = blockIdx.x >> 7;
    const int c = cgb * 128 + w * 32 + (lane >> 1);
    const int nb = (lane & 1) * 8;

    float a4[8];
    {
        const float4 a0 = *(const float4*)(A_log + c * DSTATE + nb);
        const float4 a1 = *(const float4*)(A_log + c * DSTATE + nb + 4);
        a4[0] = -__expf(a0.x); a4[1] = -__expf(a0.y);
        a4[2] = -__expf(a0.z); a4[3] = -__expf(a0.w);
        a4[4] = -__expf(a1.x); a4[5] = -__expf(a1.y);
        a4[6] = -__expf(a1.z); a4[7] = -__expf(a1.w);
    }
    float h[8] = {};
    float sumd = 0.f;

    const int s0 = b * LSEQ + k * CHUNK;
    const unsigned short* pu = uch + s0 * DI + c;
    const unsigned short* pd = delh + s0 * DI + c;
    const float* px = xdbl + s0 * 64 + DTRANK + nb;

    unsigned short dA = pd[0], uA = pu[0];
    float BA[8];
    *(float4*)&BA[0] = *(const float4*)(px);
    *(float4*)&BA[4] = *(const float4*)(px + 4);

    for (int l = 0; l < CHUNK; l += 2) {
        const unsigned short dB = pd[DI], uB = pu[DI];
        float BB[8];
        *(float4*)&BB[0] = *(const float4*)(px + 64);
        *(float4*)&BB[4] = *(const float4*)(px + 68);
        {
            const float d = bf2f(dA), u = bf2f(uA);
            const float du = d * u;
            #pragma unroll
            for (int i = 0; i < 8; ++i)
                h[i] = h[i] * __expf(d * a4[i]) + du * BA[i];
            sumd += d;
        }
        pu += 2 * DI; pd += 2 * DI; px += 128;
        dA = pd[0]; uA = pu[0];                 // over-reads 1 row on last iter
        *(float4*)&BA[0] = *(const float4*)(px);
        *(float4*)&BA[4] = *(const float4*)(px + 4);
        {
            const float d = bf2f(dB), u = bf2f(uB);
            const float du = d * u;
            #pragma unroll
            for (int i = 0; i < 8; ++i)
                h[i] = h[i] * __expf(d * a4[i]) + du * BB[i];
            sumd += d;
        }
    }

    const int pi = ((b * NCHUNK + k) * DI + c) * 16 + nb;
    *(float4*)(P + pi) = make_float4(__expf(a4[0] * sumd), __expf(a4[1] * sumd),
                                     __expf(a4[2] * sumd), __expf(a4[3] * sumd));
    *(float4*)(P + pi + 4) = make_float4(__expf(a4[4] * sumd), __expf(a4[5] * sumd),
                                         __expf(a4[6] * sumd), __expf(a4[7] * sumd));
    *(float4*)(Q + pi) = make_float4(h[0], h[1], h[2], h[3]);
    *(float4*)(Q + pi + 4) = make_float4(h[4], h[5], h[6], h[7]);
}

__global__ __launch_bounds__(256) void scan_p2(
    const float* __restrict__ P, const float* __restrict__ Q,
    float* __restrict__ HS)
{
    const int t  = blockIdx.x * 256 + threadIdx.x;   // 32768
    const int nq = (t & 3) << 2;
    const int c  = (t >> 2) & (DI - 1);
    const int b  = t >> 11;
    float4 hs = {0, 0, 0, 0};
    for (int k = 0; k < NCHUNK; ++k) {
        const int idx = ((b * NCHUNK + k) * DI + c) * 16 + nq;
        if (k > 0) {
            const int ip = idx - DI * 16;
            const float4 p4 = *(const float4*)(P + ip);
            const float4 q4 = *(const float4*)(Q + ip);
            hs.x = hs.x * p4.x + q4.x;
            hs.y = hs.y * p4.y + q4.y;
            hs.z = hs.z * p4.z + q4.z;
            hs.w = hs.w * p4.w + q4.w;
        }
        *(float4*)(HS + idx) = hs;
    }
}

__global__ __launch_bounds__(256) void scan_p3(
    const unsigned short* __restrict__ uch,
    const unsigned short* __restrict__ delh,
    const float* __restrict__ xdbl, const unsigned short* __restrict__ zuz,
    const float* __restrict__ A_log, const float* __restrict__ Dskip,
    const float* __restrict__ HS, unsigned short* __restrict__ y)
{
    const int tid = threadIdx.x;
    const int w = tid >> 6, lane = tid & 63;
    const int cgb = blockIdx.x & 3;
    const int k = (blockIdx.x >> 2) & (NCHUNK - 1);
    const int b = blockIdx.x >> 7;
    const int c = cgb * 128 + w * 32 + (lane >> 1);
    const int nb = (lane & 1) * 8;

    float a4[8];
    {
        const float4 a0 = *(const float4*)(A_log + c * DSTATE + nb);
        const float4 a1 = *(const float4*)(A_log + c * DSTATE + nb + 4);
        a4[0] = -__expf(a0.x); a4[1] = -__expf(a0.y);
        a4[2] = -__expf(a0.z); a4[3] = -__expf(a0.w);
        a4[4] = -__expf(a1.x); a4[5] = -__expf(a1.y);
        a4[6] = -__expf(a1.z); a4[7] = -__expf(a1.w);
    }
    const float dsk = Dskip[c];

    const int pi = ((b * NCHUNK + k) * DI + c) * 16 + nb;
    float h[8];
    *(float4*)&h[0] = *(const float4*)(HS + pi);
    *(float4*)&h[4] = *(const float4*)(HS + pi + 4);

    const int s0 = b * LSEQ + k * CHUNK;
    const unsigned short* pu = uch + s0 * DI + c;
    const unsigned short* pd = delh + s0 * DI + c;
    const unsigned short* pz = zuz + s0 * 1024 + c;
    const float* px = xdbl + s0 * 64 + DTRANK + nb;
    unsigned short* py = y + s0 * DI + c;

    unsigned short dA = pd[0], uA = pu[0], zA = pz[0];
    float BA[8], CA[8];
    *(float4*)&BA[0] = *(const float4*)(px);
    *(float4*)&BA[4] = *(const float4*)(px + 4);
    *(float4*)&CA[0] = *(const float4*)(px + DSTATE);
    *(float4*)&CA[4] = *(const float4*)(px + DSTATE + 4);

    for (int l = 0; l < CHUNK; l += 2) {
        const unsigned short dB = pd[DI], uB = pu[DI], zB = pz[1024];
        float BB[8], CB[8];
        *(float4*)&BB[0] = *(const float4*)(px + 64);
        *(float4*)&BB[4] = *(const float4*)(px + 68);
        *(float4*)&CB[0] = *(const float4*)(px + 64 + DSTATE);
        *(float4*)&CB[4] = *(const float4*)(px + 68 + DSTATE);
        {
            const float d = bf2f(dA), u = bf2f(uA), z = bf2f(zA);
            const float du = d * u;
            float yp = 0.f;
            #pragma unroll
            for (int i = 0; i < 8; ++i) {
                h[i] = h[i] * __expf(d * a4[i]) + du * BA[i];
                yp += h[i] * CA[i];
            }
            yp += __shfl_xor(yp, 1);
            if ((lane & 1) == 0) {
                const float sg = __builtin_amdgcn_rcpf(1.0f + __expf(-z));
                py[0] = f2bf((yp + u * dsk) * (z * sg));
            }
        }
        pu += 2 * DI; pd += 2 * DI; pz += 2048; px += 128;
        dA = pd[0]; uA = pu[0]; zA = pz[0];     // over-reads 1 row on last iter
        *(float4*)&BA[0] = *(const float4*)(px);
        *(float4*)&BA[4] = *(const float4*)(px + 4);
        *(float4*)&CA[0] = *(const float4*)(px + DSTATE);
        *(float4*)&CA[4] = *(const float4*)(px + DSTATE + 4);
        {
            const float d = bf2f(dB), u = bf2f(uB), z = bf2f(zB);
            const float du = d * u;
            float yp = 0.f;
            #pragma unroll
            for (int i = 0; i < 8; ++i) {
                h[i] = h[i] * __expf(d * a4[i]) + du * BB[i];
                yp += h[i] * CB[i];
            }
            yp += __shfl_xor(yp, 1);
            if ((lane & 1) == 0) {
                const float sg = __builtin_amdgcn_rcpf(1.0f + __expf(-z));
                py[DI] = f2bf((yp + u * dsk) * (z * sg));
            }
        }
        py += 2 * DI;
    }
}

// ---------------------------------------------------------------------------
// LayerNorm over rows of 256; optional f32 and/or bf16 outputs.
// ---------------------------------------------------------------------------
__global__ __launch_bounds__(256) void layernorm256_kernel(
    const float* __restrict__ in, const float* __restrict__ g,
    const float* __restrict__ b, float* __restrict__ out,
    unsigned short* __restrict__ out16)
{
    const int wave = threadIdx.x >> 6;
    const int lane = threadIdx.x & 63;
    const int row  = blockIdx.x * 4 + wave;

    const float4 v = ((const float4*)(in + (size_t)row * DM))[lane];
    float s  = v.x + v.y + v.z + v.w;
    float sq = v.x * v.x + v.y * v.y + v.z * v.z + v.w * v.w;
    #pragma unroll
    for (int o = 1; o < 64; o <<= 1) {
        s  += __shfl_xor(s, o);
        sq += __shfl_xor(sq, o);
    }
    const float mu  = s * (1.0f / 256.0f);
    const float var = sq * (1.0f / 256.0f) - mu * mu;
    const float rs  = rsqrtf(var + 1e-12f);

    const float4 gg = ((const float4*)g)[lane];
    const float4 bb = ((const float4*)b)[lane];
    float4 o4;
    o4.x = (v.x - mu) * rs * gg.x + bb.x;
    o4.y = (v.y - mu) * rs * gg.y + bb.y;
    o4.z = (v.z - mu) * rs * gg.z + bb.z;
    o4.w = (v.w - mu) * rs * gg.w + bb.w;
    if (out)
        ((float4*)(out + (size_t)row * DM))[lane] = o4;
    if (out16) {
        uint2 p;
        p.x = (unsigned int)f2bf(o4.x) | ((unsigned int)f2bf(o4.y) << 16);
        p.y = (unsigned int)f2bf(o4.z) | ((unsigned int)f2bf(o4.w) << 16);
        *(uint2*)(out16 + (size_t)row * DM + lane * 4) = p;
    }
}

// ---------------------------------------------------------------------------
extern "C" void kernel_launch(void* const* d_in, const int* in_sizes, int n_in,
                              void* d_out, int out_size, void* d_ws, size_t ws_size,
                              hipStream_t stream)
{
    const float* x          = (const float*)d_in[0];
    const float* in_proj_w  = (const float*)d_in[1];
    const float* conv_w     = (const float*)d_in[2];
    const float* conv_b     = (const float*)d_in[3];
    const float* x_proj_w   = (const float*)d_in[4];
    const float* dt_proj_w  = (const float*)d_in[5];
    const float* dt_proj_b  = (const float*)d_in[6];
    const float* A_log      = (const float*)d_in[7];
    const float* Dskip      = (const float*)d_in[8];
    const float* out_proj_w = (const float*)d_in[9];
    const float* ln1_g      = (const float*)d_in[10];
    const float* ln1_b      = (const float*)d_in[11];
    const float* w1         = (const float*)d_in[12];
    const float* b1         = (const float*)d_in[13];
    const float* w2         = (const float*)d_in[14];
    const float* b2         = (const float*)d_in[15];
    const float* ln2_g      = (const float*)d_in[16];
    const float* ln2_b      = (const float*)d_in[17];
    float* out = (float*)d_out;
    char*  ws8 = (char*)d_ws;

    const size_t Mi = 1048576;
    // Workspace map (byte offsets, ~220 Mi used):
    //  [  0, 64Mi): uz bf16 [S,1024]    -> after p3: M f32 [0,32), F2 f32 [32,64)
    //  [ 64, 96Mi): uch bf16 [S,512]    -> y bf16 in-place
    //  [ 96,104Mi): x_dbl f32 [S,64]
    //  [104,168Mi): FF bf16 [S,1024]; during scan: P[104,120) Q[120,136) HS[136,152)
    //  [168,184Mi): H1h bf16 [S,256]
    //  [184,186Mi): xdblh bf16 [S,32]
    //  [186,218Mi): delh bf16 [S,512]
    //  [218,220Mi): bf16 weights
    unsigned short* bufUZ  = (unsigned short*)(ws8);
    unsigned short* bufUCh = (unsigned short*)(ws8 + 64 * Mi);
    float*          bufXD  = (float*)(ws8 + 96 * Mi);
    unsigned short* bufFF  = (unsigned short*)(ws8 + 104 * Mi);
    float*          bufP   = (float*)(ws8 + 104 * Mi);
    float*          bufQ   = (float*)(ws8 + 120 * Mi);
    float*          bufHS  = (float*)(ws8 + 136 * Mi);
    unsigned short* bufH1h = (unsigned short*)(ws8 + 168 * Mi);
    unsigned short* bufXDh = (unsigned short*)(ws8 + 184 * Mi);
    unsigned short* bufDelh= (unsigned short*)(ws8 + 186 * Mi);
    unsigned short* wb     = (unsigned short*)(ws8 + 218 * Mi);

    float*          bufM   = (float*)(ws8);                      // over uz lo
    float*          bufF2  = (float*)(ws8 + 32 * Mi);            // over uz hi
    unsigned short* bufY   = bufUCh;

    unsigned short* wInP16 = wb;
    unsigned short* wXP16  = wb + 262144;
    unsigned short* wOP16  = wb + 286720;
    unsigned short* wW116  = wb + 417792;
    unsigned short* wW216  = wb + 679936;
    unsigned short* wDTp16 = wb + 942080;

    unsigned short* x16 = (unsigned short*)d_out;

    const dim3 blk(256);
    const int MT = S_TOTAL / 128;   // 256 row tiles

    // 0) cast x + weights to bf16 (incl. zero-padded dtw [512,32])
    convert_kernel<<<dim3(36512), blk, 0, stream>>>(
        x, in_proj_w, x_proj_w, out_proj_w, w1, w2, dt_proj_w, x16, wb);

    // 1) in_proj (merged u|z) -> uz bf16 [S,1024]
    gemm_bf16<EPI_NONE, true><<<dim3(8, MT), blk, 0, stream>>>(
        x16, DM, wInP16, DM, nullptr, nullptr, 0, bufUZ, 1024, 1024, DM, 1023,
        nullptr, 0);

    // 2) depthwise causal conv + SiLU -> uch bf16
    conv_silu_kernel<<<dim3(S_TOTAL * 64 / 256), blk, 0, stream>>>(
        bufUZ, conv_w, conv_b, bufUCh);

    // 3) x_proj -> x_dbl f32 [S,64] (48 valid) + bf16 aux [S,32] (dt cols)
    gemm_bf16<EPI_NONE, false><<<dim3(1, MT), blk, 0, stream>>>(
        bufUCh, DI, wXP16, DI, nullptr, nullptr, 0, bufXD, 64, 48, DI, 47,
        bufXDh, 32);

    // 4) dt_proj + softplus as K=32 MFMA GEMM -> delh bf16 [S,512]
    gemm_bf16<EPI_SOFTPLUS_BIAS, true><<<dim3(4, MT), blk, 0, stream>>>(
        bufXDh, 32, wDTp16, 32, dt_proj_b, nullptr, 0, bufDelh, DI, DI, 32, 511,
        nullptr, 0);

    // 5) chunked selective scan -> y bf16 (in place over uch)
    scan_p1<<<dim3(NBATCH * NCHUNK * 4), blk, 0, stream>>>(
        bufUCh, bufDelh, bufXD, A_log, bufP, bufQ);
    scan_p2<<<dim3(S_TOTAL / 256), blk, 0, stream>>>(
        bufP, bufQ, bufHS);
    scan_p3<<<dim3(NBATCH * NCHUNK * 4), blk, 0, stream>>>(
        bufUCh, bufDelh, bufXD, bufUZ + 512, A_log, Dskip, bufHS, bufY);

    // 6) out_proj + residual x (bf16) -> M f32 (pre-LN1)
    gemm_bf16<EPI_RESID16, false><<<dim3(2, MT), blk, 0, stream>>>(
        bufY, DI, wOP16, DI, nullptr, x16, DM, bufM, DM, 256, DI, 255,
        nullptr, 0);

    // 7) LN1 -> h1 bf16 only
    layernorm256_kernel<<<dim3(S_TOTAL / 4), blk, 0, stream>>>(
        bufM, ln1_g, ln1_b, nullptr, bufH1h);

    // 8) ff1: gelu(h1 @ w1^T + b1) -> FF bf16
    gemm_bf16<EPI_GELU_BIAS, true><<<dim3(8, MT), blk, 0, stream>>>(
        bufH1h, DM, wW116, DM, b1, nullptr, 0, bufFF, 1024, 1024, DM, 1023,
        nullptr, 0);

    // 9) ff2 + b2 + h1 (bf16 resid) -> F2 f32 (pre-LN2)
    gemm_bf16<EPI_BIAS_RESID16, false><<<dim3(2, MT), blk, 0, stream>>>(
        bufFF, 1024, wW216, 1024, b2, bufH1h, DM, bufF2, DM, 256, 1024, 255,
        nullptr, 0);

    // 10) LN2 -> out
    layernorm256_kernel<<<dim3(S_TOTAL / 4), blk, 0, stream>>>(
        bufF2, ln2_g, ln2_b, out, nullptr);
}